// Round 1
// baseline (1393.717 us; speedup 1.0000x reference)
//
#include <hip/hip_runtime.h>
#include <math.h>

#define DMQ 768
#define DIQ 1536
#define LSEQ 2048
#define BATCH 2
#define NST 16
#define RR 48
#define KDIM 80   // R + 2N
#define EPSQ 1e-5f

static __device__ __forceinline__ float silu_f(float x) {
    return x / (1.f + __expf(-x));
}
static __device__ __forceinline__ float softplus_f(float x) {
    return (x > 20.f) ? x : log1pf(__expf(x));
}

// ---------------------------------------------------------------------------
// K1: residual = x + residual ; xn = rmsnorm(residual) * norm_w
// one block per row (DM=768), 256 threads
// ---------------------------------------------------------------------------
__launch_bounds__(256)
__global__ void rmsnorm_k(const float* __restrict__ x, const float* __restrict__ res,
                          const float* __restrict__ w, float* __restrict__ res_out,
                          float* __restrict__ xn) {
    int row = blockIdx.x;
    int tid = threadIdx.x;
    size_t base = (size_t)row * DMQ;
    float v[3];
    float ss = 0.f;
#pragma unroll
    for (int i = 0; i < 3; ++i) {
        int c = tid + i * 256;
        float r = x[base + c] + res[base + c];
        v[i] = r;
        ss = fmaf(r, r, ss);
        res_out[base + c] = r;
    }
#pragma unroll
    for (int off = 1; off < 64; off <<= 1) ss += __shfl_xor(ss, off);
    __shared__ float sbuf[4];
    if ((tid & 63) == 0) sbuf[tid >> 6] = ss;
    __syncthreads();
    float tot = sbuf[0] + sbuf[1] + sbuf[2] + sbuf[3];
    float inv = rsqrtf(tot / (float)DMQ + EPSQ);
#pragma unroll
    for (int i = 0; i < 3; ++i) {
        int c = tid + i * 256;
        xn[base + c] = v[i] * inv * w[c];
    }
}

// ---------------------------------------------------------------------------
// Generic fp32 GEMM: C[M,N] = A[M,K] * B  (+ epilogue)
// BT=false: B is K x N row-major (ldb = row stride)
// BT=true : B is N x K row-major (ldb = row stride) -> C = A * B^T
// EPI==1  : C = softplus(acc + bias[n])
// tile 64x64, BK=16, 256 threads, 4x4 per thread
// Requires: M % 64 == 0, K % 16 == 0. N guarded.
// ---------------------------------------------------------------------------
template <bool BT, int EPI>
__launch_bounds__(256)
__global__ void gemm64(const float* __restrict__ A, const float* __restrict__ B,
                       const float* __restrict__ bias, float* __restrict__ C,
                       int M, int N, int K, int lda, int ldb, int ldc) {
    constexpr int BM = 64, BN = 64, BK = 16;
    __shared__ float As[BK][BM + 4];
    __shared__ float Bs[BK][BN + 4];
    const int tid = threadIdx.x;
    const int tx = tid & 15, ty = tid >> 4;
    const int bm = blockIdx.y * BM;
    const int bn = blockIdx.x * BN;
    float acc[4][4] = {};
    for (int k0 = 0; k0 < K; k0 += BK) {
#pragma unroll
        for (int i = 0; i < 4; ++i) {
            int t = tid + i * 256;
            int m = t >> 4;
            int kk = t & 15;
            As[kk][m] = A[(size_t)(bm + m) * lda + k0 + kk];
        }
#pragma unroll
        for (int i = 0; i < 4; ++i) {
            int t = tid + i * 256;
            if (!BT) {
                int kk = t >> 6;
                int n = t & 63;
                float v = 0.f;
                if (bn + n < N) v = B[(size_t)(k0 + kk) * ldb + bn + n];
                Bs[kk][n] = v;
            } else {
                int n = t >> 4;
                int kk = t & 15;
                float v = 0.f;
                if (bn + n < N) v = B[(size_t)(bn + n) * ldb + k0 + kk];
                Bs[kk][n] = v;
            }
        }
        __syncthreads();
#pragma unroll
        for (int kk = 0; kk < BK; ++kk) {
            float4 av = *(const float4*)&As[kk][ty * 4];
            float4 bv = *(const float4*)&Bs[kk][tx * 4];
            float a[4] = {av.x, av.y, av.z, av.w};
            float b[4] = {bv.x, bv.y, bv.z, bv.w};
#pragma unroll
            for (int i = 0; i < 4; ++i)
#pragma unroll
                for (int j = 0; j < 4; ++j)
                    acc[i][j] = fmaf(a[i], b[j], acc[i][j]);
        }
        __syncthreads();
    }
#pragma unroll
    for (int i = 0; i < 4; ++i) {
        int m = bm + ty * 4 + i;
#pragma unroll
        for (int j = 0; j < 4; ++j) {
            int n = bn + tx * 4 + j;
            if (n < N) {
                float v = acc[i][j];
                if (EPI == 1) v = softplus_f(v + bias[n]);
                C[(size_t)m * ldc + n] = v;
            }
        }
    }
}

// ---------------------------------------------------------------------------
// K3: depthwise causal-padded conv (kernel 3, pad 1) + bias + silu
// xc = xz[:, :DI]; u[row, d] written (B*L, DI). float4 over d.
// ---------------------------------------------------------------------------
__launch_bounds__(256)
__global__ void conv_silu_k(const float* __restrict__ xz, const float* __restrict__ cw,
                            const float* __restrict__ cb, float* __restrict__ u) {
    int idx = blockIdx.x * 256 + threadIdx.x;  // B*L*(DI/4) total
    const int nd4 = DIQ / 4;                   // 384
    int row = idx / nd4;
    int d = (idx - row * nd4) * 4;
    int l = row & (LSEQ - 1);
    const float* p = xz + (size_t)row * (2 * DIQ) + d;
    float a0[4] = {0.f, 0.f, 0.f, 0.f};
    float a1[4];
    float a2[4] = {0.f, 0.f, 0.f, 0.f};
    *(float4*)a1 = *(const float4*)p;
    if (l > 0) *(float4*)a0 = *(const float4*)(p - 2 * DIQ);
    if (l < LSEQ - 1) *(float4*)a2 = *(const float4*)(p + 2 * DIQ);
    float4 ov;
    float* o = (float*)&ov;
#pragma unroll
    for (int j = 0; j < 4; ++j) {
        float s = cb[d + j];
        s = fmaf(a0[j], cw[(d + j) * 3 + 0], s);
        s = fmaf(a1[j], cw[(d + j) * 3 + 1], s);
        s = fmaf(a2[j], cw[(d + j) * 3 + 2], s);
        o[j] = silu_f(s);
    }
    *(float4*)(u + (size_t)row * DIQ + d) = ov;
}

// ---------------------------------------------------------------------------
// K6: selective scan. One wave (64 threads) per 4 channels; lane = ch*16 + n.
// h recurrence kept in a register; y-reduce via shfl_xor within 16-lane group.
// ---------------------------------------------------------------------------
__launch_bounds__(64)
__global__ void scan_k(const float* __restrict__ delta, const float* __restrict__ u,
                       const float* __restrict__ xdbl, const float* __restrict__ Alog,
                       const float* __restrict__ Dp, float* __restrict__ y) {
    const int nch = DIQ / 4;  // 384 blocks per batch
    int blk = blockIdx.x;
    int b = blk / nch;
    int d = (blk - b * nch) * 4 + (threadIdx.x >> 4);
    int n = threadIdx.x & 15;
    float a = -__expf(Alog[d * NST + n]);
    float Dd = Dp[d];
    float h = 0.f;
    size_t rbase = (size_t)b * LSEQ;
    // prefetch l = 0
    float dlt = delta[rbase * DIQ + d];
    float uu = u[rbase * DIQ + d];
    float bv = xdbl[rbase * KDIM + RR + n];
    float cv = xdbl[rbase * KDIM + RR + NST + n];
    for (int l = 0; l < LSEQ; ++l) {
        float dlt_n = 0.f, uu_n = 0.f, bv_n = 0.f, cv_n = 0.f;
        if (l + 1 < LSEQ) {
            size_t r = rbase + l + 1;
            dlt_n = delta[r * DIQ + d];
            uu_n = u[r * DIQ + d];
            bv_n = xdbl[r * KDIM + RR + n];
            cv_n = xdbl[r * KDIM + RR + NST + n];
        }
        float dA = __expf(dlt * a);
        h = fmaf(dA, h, dlt * uu * bv);
        float yc = h * cv;
        yc += __shfl_xor(yc, 1);
        yc += __shfl_xor(yc, 2);
        yc += __shfl_xor(yc, 4);
        yc += __shfl_xor(yc, 8);
        if (n == 0) y[(rbase + l) * DIQ + d] = fmaf(uu, Dd, yc);
        dlt = dlt_n; uu = uu_n; bv = bv_n; cv = cv_n;
    }
}

// ---------------------------------------------------------------------------
// K7: layernorm(y) * ln_w + ln_b, gated by silu(z); z = xz[:, DI:2*DI]
// one block per row (DI=1536), 256 threads
// ---------------------------------------------------------------------------
__launch_bounds__(256)
__global__ void lngate_k(const float* __restrict__ y, const float* __restrict__ xz,
                         const float* __restrict__ lw, const float* __restrict__ lb,
                         float* __restrict__ g) {
    int row = blockIdx.x;
    int tid = threadIdx.x;
    size_t ybase = (size_t)row * DIQ;
    float v[6];
    float s = 0.f, sq = 0.f;
#pragma unroll
    for (int i = 0; i < 6; ++i) {
        int c = tid + i * 256;
        float t = y[ybase + c];
        v[i] = t;
        s += t;
        sq = fmaf(t, t, sq);
    }
#pragma unroll
    for (int off = 1; off < 64; off <<= 1) {
        s += __shfl_xor(s, off);
        sq += __shfl_xor(sq, off);
    }
    __shared__ float ssb[4], sqb[4];
    if ((tid & 63) == 0) {
        ssb[tid >> 6] = s;
        sqb[tid >> 6] = sq;
    }
    __syncthreads();
    s = ssb[0] + ssb[1] + ssb[2] + ssb[3];
    sq = sqb[0] + sqb[1] + sqb[2] + sqb[3];
    float mu = s / (float)DIQ;
    float var = sq / (float)DIQ - mu * mu;
    float inv = rsqrtf(var + EPSQ);
#pragma unroll
    for (int i = 0; i < 6; ++i) {
        int c = tid + i * 256;
        float t = (v[i] - mu) * inv * lw[c] + lb[c];
        float z = xz[(size_t)row * (2 * DIQ) + DIQ + c];
        g[ybase + c] = t * silu_f(z);
    }
}

// ---------------------------------------------------------------------------
extern "C" void kernel_launch(void* const* d_in, const int* in_sizes, int n_in,
                              void* d_out, int out_size, void* d_ws, size_t ws_size,
                              hipStream_t stream) {
    const float* x         = (const float*)d_in[0];
    const float* residual  = (const float*)d_in[1];
    const float* norm_w    = (const float*)d_in[2];
    const float* in_proj_w = (const float*)d_in[3];
    const float* conv_w    = (const float*)d_in[4];
    const float* conv_b    = (const float*)d_in[5];
    const float* x_proj_w  = (const float*)d_in[6];
    const float* dt_proj_w = (const float*)d_in[7];
    const float* dt_proj_b = (const float*)d_in[8];
    const float* A_log     = (const float*)d_in[9];
    const float* Dp        = (const float*)d_in[10];
    const float* ln_w      = (const float*)d_in[11];
    const float* ln_b      = (const float*)d_in[12];
    const float* out_proj_w= (const float*)d_in[13];

    float* out = (float*)d_out;                               // (B,L,DM)
    float* res_out = out + (size_t)BATCH * LSEQ * DMQ;        // (B,L,DM)

    const int ROWS = BATCH * LSEQ;  // 4096
    float* xz   = (float*)d_ws;                         // ROWS * 3072
    float* xn   = xz + (size_t)ROWS * 2 * DIQ;          // ROWS * 768  (reused as x_dbl)
    float* u    = xn + (size_t)ROWS * DMQ;              // ROWS * 1536
    float* dl   = u  + (size_t)ROWS * DIQ;              // ROWS * 1536 (delta -> ygate)
    float* yb   = dl + (size_t)ROWS * DIQ;              // ROWS * 1536
    float* xdbl = xn;                                   // ROWS * 80 fits in xn slot
    float* gate = dl;

    // K1: add + RMSNorm (writes residual output half of d_out)
    rmsnorm_k<<<ROWS, 256, 0, stream>>>(x, residual, norm_w, res_out, xn);

    // K2: xz = xn @ in_proj_w   (4096 x 3072 x 768)
    {
        dim3 g(2 * DIQ / 64, ROWS / 64);
        gemm64<false, 0><<<g, 256, 0, stream>>>(xn, in_proj_w, nullptr, xz,
                                                ROWS, 2 * DIQ, DMQ, DMQ, 2 * DIQ, 2 * DIQ);
    }

    // K3: depthwise conv + bias + silu -> u
    conv_silu_k<<<ROWS * (DIQ / 4) / 256, 256, 0, stream>>>(xz, conv_w, conv_b, u);

    // K4: x_dbl = u @ x_proj_w   (4096 x 80 x 1536)
    {
        dim3 g((KDIM + 63) / 64, ROWS / 64);
        gemm64<false, 0><<<g, 256, 0, stream>>>(u, x_proj_w, nullptr, xdbl,
                                                ROWS, KDIM, DIQ, DIQ, KDIM, KDIM);
    }

    // K5: delta = softplus(dts @ dt_proj_w^T + dt_proj_b)   (4096 x 1536 x 48)
    {
        dim3 g(DIQ / 64, ROWS / 64);
        gemm64<true, 1><<<g, 256, 0, stream>>>(xdbl, dt_proj_w, dt_proj_b, dl,
                                               ROWS, DIQ, RR, KDIM, RR, DIQ);
    }

    // K6: selective scan -> y (includes + u*D)
    scan_k<<<BATCH * (DIQ / 4), 64, 0, stream>>>(dl, u, xdbl, A_log, Dp, yb);

    // K7: layernorm + silu(z) gate -> gate (reuses delta buffer)
    lngate_k<<<ROWS, 256, 0, stream>>>(yb, xz, ln_w, ln_b, gate);

    // K8: out = gate @ out_proj_w   (4096 x 768 x 1536)
    {
        dim3 g(DMQ / 64, ROWS / 64);
        gemm64<false, 0><<<g, 256, 0, stream>>>(gate, out_proj_w, nullptr, out,
                                                ROWS, DMQ, DIQ, DIQ, DMQ, DMQ);
    }
}

// Round 3
// 888.987 us; speedup vs baseline: 1.5678x; 1.5678x over previous
//
#include <hip/hip_runtime.h>
#include <math.h>

#define DMQ 768
#define DIQ 1536
#define LSEQ 2048
#define BATCH 2
#define NST 16
#define RR 48
#define KDIM 80   // R + 2N
#define EPSQ 1e-5f
#define CCH 16    // scan chunks
#define TCH 128   // chunk length (LSEQ / CCH)

static __device__ __forceinline__ float silu_f(float x) {
    return x / (1.f + __expf(-x));
}
static __device__ __forceinline__ float softplus_f(float x) {
    return (x > 20.f) ? x : log1pf(__expf(x));
}

// ---------------------------------------------------------------------------
// K1: residual = x + residual ; xn = rmsnorm(residual) * norm_w
// ---------------------------------------------------------------------------
__launch_bounds__(256)
__global__ void rmsnorm_k(const float* __restrict__ x, const float* __restrict__ res,
                          const float* __restrict__ w, float* __restrict__ res_out,
                          float* __restrict__ xn) {
    int row = blockIdx.x;
    int tid = threadIdx.x;
    size_t base = (size_t)row * DMQ;
    float v[3];
    float ss = 0.f;
#pragma unroll
    for (int i = 0; i < 3; ++i) {
        int c = tid + i * 256;
        float r = x[base + c] + res[base + c];
        v[i] = r;
        ss = fmaf(r, r, ss);
        res_out[base + c] = r;
    }
#pragma unroll
    for (int off = 1; off < 64; off <<= 1) ss += __shfl_xor(ss, off);
    __shared__ float sbuf[4];
    if ((tid & 63) == 0) sbuf[tid >> 6] = ss;
    __syncthreads();
    float tot = sbuf[0] + sbuf[1] + sbuf[2] + sbuf[3];
    float inv = rsqrtf(tot / (float)DMQ + EPSQ);
#pragma unroll
    for (int i = 0; i < 3; ++i) {
        int c = tid + i * 256;
        xn[base + c] = v[i] * inv * w[c];
    }
}

// ---------------------------------------------------------------------------
// Big-tile fp32 GEMM: C[M,N] = A[M,K] @ B[K,N]  (row-major, no transpose)
// BM x BN tile, BK=16, 256 threads, (BM/16)x(BN/16) per thread in 4-wide spans.
// Requires M%BM==0, N%BN==0, K%16==0.
// ---------------------------------------------------------------------------
template <int BM, int BN, int EPI>
__launch_bounds__(256)
__global__ void gemm_t(const float* __restrict__ A, const float* __restrict__ B,
                       const float* __restrict__ bias, float* __restrict__ C,
                       int K, int lda, int ldb, int ldc) {
    constexpr int BK = 16;
    constexpr int HA = BM / 64, HB = BN / 64;
    __shared__ float As[BK][BM + 4];
    __shared__ float Bs[BK][BN + 4];
    const int tid = threadIdx.x;
    const int tx = tid & 15, ty = tid >> 4;
    const int bm = blockIdx.y * BM;
    const int bn = blockIdx.x * BN;
    float acc[HA * 4][HB * 4] = {};
    for (int k0 = 0; k0 < K; k0 += BK) {
        // ---- stage A (transpose to As[kk][m]) ----
        if constexpr (BM == 128) {
            int m = tid >> 1, kg = (tid & 1) * 8;
            const float* ap = &A[(size_t)(bm + m) * lda + k0 + kg];
            float4 v0 = *(const float4*)ap;
            float4 v1 = *(const float4*)(ap + 4);
            As[kg + 0][m] = v0.x; As[kg + 1][m] = v0.y;
            As[kg + 2][m] = v0.z; As[kg + 3][m] = v0.w;
            As[kg + 4][m] = v1.x; As[kg + 5][m] = v1.y;
            As[kg + 6][m] = v1.z; As[kg + 7][m] = v1.w;
        } else {
            int m = tid >> 2, kg = (tid & 3) * 4;
            float4 v0 = *(const float4*)&A[(size_t)(bm + m) * lda + k0 + kg];
            As[kg + 0][m] = v0.x; As[kg + 1][m] = v0.y;
            As[kg + 2][m] = v0.z; As[kg + 3][m] = v0.w;
        }
        // ---- stage B (direct) ----
        {
            int kk = tid >> 4, c = (tid & 15) * 4;
            const float* bp = &B[(size_t)(k0 + kk) * ldb + bn];
            *(float4*)&Bs[kk][c] = *(const float4*)(bp + c);
            if constexpr (BN == 128)
                *(float4*)&Bs[kk][c + 64] = *(const float4*)(bp + c + 64);
        }
        __syncthreads();
#pragma unroll
        for (int kk = 0; kk < BK; ++kk) {
            float a[HA * 4], b[HB * 4];
#pragma unroll
            for (int h = 0; h < HA; ++h)
                *(float4*)&a[h * 4] = *(const float4*)&As[kk][ty * 4 + h * 64];
#pragma unroll
            for (int h = 0; h < HB; ++h)
                *(float4*)&b[h * 4] = *(const float4*)&Bs[kk][tx * 4 + h * 64];
#pragma unroll
            for (int i = 0; i < HA * 4; ++i)
#pragma unroll
                for (int j = 0; j < HB * 4; ++j)
                    acc[i][j] = fmaf(a[i], b[j], acc[i][j]);
        }
        __syncthreads();
    }
#pragma unroll
    for (int i = 0; i < HA * 4; ++i) {
        int m = bm + (i >> 2) * 64 + ty * 4 + (i & 3);
#pragma unroll
        for (int h = 0; h < HB; ++h) {
            int n0 = bn + h * 64 + tx * 4;
            float4 v;
            float* vp = (float*)&v;
#pragma unroll
            for (int j = 0; j < 4; ++j) {
                float t = acc[i][h * 4 + j];
                if (EPI == 1) t = softplus_f(t + bias[n0 + j]);
                vp[j] = t;
            }
            *(float4*)&C[(size_t)m * ldc + n0] = v;
        }
    }
}

// ---------------------------------------------------------------------------
// Legacy 64x64 GEMM for the small-N cases (x_proj, dt_proj).
// ---------------------------------------------------------------------------
template <bool BT, int EPI>
__launch_bounds__(256)
__global__ void gemm64(const float* __restrict__ A, const float* __restrict__ B,
                       const float* __restrict__ bias, float* __restrict__ C,
                       int M, int N, int K, int lda, int ldb, int ldc) {
    constexpr int BM = 64, BN = 64, BK = 16;
    __shared__ float As[BK][BM + 4];
    __shared__ float Bs[BK][BN + 4];
    const int tid = threadIdx.x;
    const int tx = tid & 15, ty = tid >> 4;
    const int bm = blockIdx.y * BM;
    const int bn = blockIdx.x * BN;
    float acc[4][4] = {};
    for (int k0 = 0; k0 < K; k0 += BK) {
#pragma unroll
        for (int i = 0; i < 4; ++i) {
            int t = tid + i * 256;
            int m = t >> 4;
            int kk = t & 15;
            As[kk][m] = A[(size_t)(bm + m) * lda + k0 + kk];
        }
#pragma unroll
        for (int i = 0; i < 4; ++i) {
            int t = tid + i * 256;
            if (!BT) {
                int kk = t >> 6;
                int n = t & 63;
                float v = 0.f;
                if (bn + n < N) v = B[(size_t)(k0 + kk) * ldb + bn + n];
                Bs[kk][n] = v;
            } else {
                int n = t >> 4;
                int kk = t & 15;
                float v = 0.f;
                if (bn + n < N) v = B[(size_t)(bn + n) * ldb + k0 + kk];
                Bs[kk][n] = v;
            }
        }
        __syncthreads();
#pragma unroll
        for (int kk = 0; kk < BK; ++kk) {
            float4 av = *(const float4*)&As[kk][ty * 4];
            float4 bv = *(const float4*)&Bs[kk][tx * 4];
            float a[4] = {av.x, av.y, av.z, av.w};
            float b[4] = {bv.x, bv.y, bv.z, bv.w};
#pragma unroll
            for (int i = 0; i < 4; ++i)
#pragma unroll
                for (int j = 0; j < 4; ++j)
                    acc[i][j] = fmaf(a[i], b[j], acc[i][j]);
        }
        __syncthreads();
    }
#pragma unroll
    for (int i = 0; i < 4; ++i) {
        int m = bm + ty * 4 + i;
#pragma unroll
        for (int j = 0; j < 4; ++j) {
            int n = bn + tx * 4 + j;
            if (n < N) {
                float v = acc[i][j];
                if (EPI == 1) v = softplus_f(v + bias[n]);
                C[(size_t)m * ldc + n] = v;
            }
        }
    }
}

// ---------------------------------------------------------------------------
// K3: depthwise causal-padded conv (kernel 3, pad 1) + bias + silu
// ---------------------------------------------------------------------------
__launch_bounds__(256)
__global__ void conv_silu_k(const float* __restrict__ xz, const float* __restrict__ cw,
                            const float* __restrict__ cb, float* __restrict__ u) {
    int idx = blockIdx.x * 256 + threadIdx.x;
    const int nd4 = DIQ / 4;
    int row = idx / nd4;
    int d = (idx - row * nd4) * 4;
    int l = row & (LSEQ - 1);
    const float* p = xz + (size_t)row * (2 * DIQ) + d;
    float a0[4] = {0.f, 0.f, 0.f, 0.f};
    float a1[4];
    float a2[4] = {0.f, 0.f, 0.f, 0.f};
    *(float4*)a1 = *(const float4*)p;
    if (l > 0) *(float4*)a0 = *(const float4*)(p - 2 * DIQ);
    if (l < LSEQ - 1) *(float4*)a2 = *(const float4*)(p + 2 * DIQ);
    float4 ov;
    float* o = (float*)&ov;
#pragma unroll
    for (int j = 0; j < 4; ++j) {
        float s = cb[d + j];
        s = fmaf(a0[j], cw[(d + j) * 3 + 0], s);
        s = fmaf(a1[j], cw[(d + j) * 3 + 1], s);
        s = fmaf(a2[j], cw[(d + j) * 3 + 2], s);
        o[j] = silu_f(s);
    }
    *(float4*)(u + (size_t)row * DIQ + d) = ov;
}

// ---------------------------------------------------------------------------
// Chunked selective scan.
// Pass 1: per chunk, local scan from h=0; store h_end and P = prod(dA).
// Combine: sequential over the 16 chunks -> chunk start states.
// Pass 3: re-scan each chunk from its true start state, emit y.
// lane = (channel-within-group-of-4)*16 + n ; wave covers 4 channels x 16 states.
// ---------------------------------------------------------------------------
__launch_bounds__(64)
__global__ void scan1_k(const float* __restrict__ delta, const float* __restrict__ u,
                        const float* __restrict__ xdbl, const float* __restrict__ Alog,
                        float* __restrict__ hend, float* __restrict__ Pp) {
    const int ngrp = DIQ / 4;  // 384
    int blk = blockIdx.x;
    int dg = blk % ngrp;
    int c = (blk / ngrp) % CCH;
    int b = blk / (ngrp * CCH);
    int d = dg * 4 + (threadIdx.x >> 4);
    int n = threadIdx.x & 15;
    float a = -__expf(Alog[d * NST + n]);
    size_t r0 = (size_t)b * LSEQ + (size_t)c * TCH;
    const float* pd = delta + r0 * DIQ + d;
    const float* pu = u + r0 * DIQ + d;
    const float* pb = xdbl + r0 * KDIM + RR + n;
    float h = 0.f, P = 1.f;
    float dlt = *pd, uu = *pu, bv = *pb;
    for (int t = 0; t < TCH; ++t) {
        float dlt_n = 0.f, uu_n = 0.f, bv_n = 0.f;
        if (t + 1 < TCH) {
            pd += DIQ; pu += DIQ; pb += KDIM;
            dlt_n = *pd; uu_n = *pu; bv_n = *pb;
        }
        float dA = __expf(dlt * a);
        h = fmaf(dA, h, dlt * uu * bv);
        P *= dA;
        dlt = dlt_n; uu = uu_n; bv = bv_n;
    }
    size_t idx = (((size_t)b * CCH + c) * DIQ + d) * NST + n;
    hend[idx] = h;
    Pp[idx] = P;
}

__launch_bounds__(64)
__global__ void scan_combine_k(const float* __restrict__ hend, const float* __restrict__ Pp,
                               float* __restrict__ Hstart) {
    const int ngrp = DIQ / 4;
    int blk = blockIdx.x;  // b*384 + dg
    int b = blk / ngrp;
    int dg = blk % ngrp;
    int d = dg * 4 + (threadIdx.x >> 4);
    int n = threadIdx.x & 15;
    size_t base = ((size_t)b * CCH) * DIQ * NST + (size_t)d * NST + n;
    const size_t cs = (size_t)DIQ * NST;
    float H = 0.f;
#pragma unroll
    for (int c = 0; c < CCH; ++c) {
        Hstart[base + c * cs] = H;
        H = fmaf(Pp[base + c * cs], H, hend[base + c * cs]);
    }
}

__launch_bounds__(64)
__global__ void scan3_k(const float* __restrict__ delta, const float* __restrict__ u,
                        const float* __restrict__ xdbl, const float* __restrict__ Alog,
                        const float* __restrict__ Dp, const float* __restrict__ Hstart,
                        float* __restrict__ y) {
    const int ngrp = DIQ / 4;
    int blk = blockIdx.x;
    int dg = blk % ngrp;
    int c = (blk / ngrp) % CCH;
    int b = blk / (ngrp * CCH);
    int d = dg * 4 + (threadIdx.x >> 4);
    int n = threadIdx.x & 15;
    float a = -__expf(Alog[d * NST + n]);
    float Dd = Dp[d];
    size_t idx = (((size_t)b * CCH + c) * DIQ + d) * NST + n;
    float h = Hstart[idx];
    size_t r0 = (size_t)b * LSEQ + (size_t)c * TCH;
    const float* pd = delta + r0 * DIQ + d;
    const float* pu = u + r0 * DIQ + d;
    const float* pb = xdbl + r0 * KDIM + RR + n;
    const float* pc = xdbl + r0 * KDIM + RR + NST + n;
    float* py = y + r0 * DIQ + d;
    float dlt = *pd, uu = *pu, bv = *pb, cv = *pc;
    for (int t = 0; t < TCH; ++t) {
        float dlt_n = 0.f, uu_n = 0.f, bv_n = 0.f, cv_n = 0.f;
        if (t + 1 < TCH) {
            pd += DIQ; pu += DIQ; pb += KDIM; pc += KDIM;
            dlt_n = *pd; uu_n = *pu; bv_n = *pb; cv_n = *pc;
        }
        float dA = __expf(dlt * a);
        h = fmaf(dA, h, dlt * uu * bv);
        float yc = h * cv;
        yc += __shfl_xor(yc, 1);
        yc += __shfl_xor(yc, 2);
        yc += __shfl_xor(yc, 4);
        yc += __shfl_xor(yc, 8);
        if (n == 0) py[(size_t)t * DIQ] = fmaf(uu, Dd, yc);
        dlt = dlt_n; uu = uu_n; bv = bv_n; cv = cv_n;
    }
}

// ---------------------------------------------------------------------------
// K7: layernorm(y) * ln_w + ln_b, gated by silu(z)
// ---------------------------------------------------------------------------
__launch_bounds__(256)
__global__ void lngate_k(const float* __restrict__ y, const float* __restrict__ xz,
                         const float* __restrict__ lw, const float* __restrict__ lb,
                         float* __restrict__ g) {
    int row = blockIdx.x;
    int tid = threadIdx.x;
    size_t ybase = (size_t)row * DIQ;
    float v[6];
    float s = 0.f, sq = 0.f;
#pragma unroll
    for (int i = 0; i < 6; ++i) {
        int c = tid + i * 256;
        float t = y[ybase + c];
        v[i] = t;
        s += t;
        sq = fmaf(t, t, sq);
    }
#pragma unroll
    for (int off = 1; off < 64; off <<= 1) {
        s += __shfl_xor(s, off);
        sq += __shfl_xor(sq, off);
    }
    __shared__ float ssb[4], sqb[4];
    if ((tid & 63) == 0) {
        ssb[tid >> 6] = s;
        sqb[tid >> 6] = sq;
    }
    __syncthreads();
    s = ssb[0] + ssb[1] + ssb[2] + ssb[3];
    sq = sqb[0] + sqb[1] + sqb[2] + sqb[3];
    float mu = s / (float)DIQ;
    float var = sq / (float)DIQ - mu * mu;
    float inv = rsqrtf(var + EPSQ);
#pragma unroll
    for (int i = 0; i < 6; ++i) {
        int c = tid + i * 256;
        float t = (v[i] - mu) * inv * lw[c] + lb[c];
        float z = xz[(size_t)row * (2 * DIQ) + DIQ + c];
        g[ybase + c] = t * silu_f(z);
    }
}

// ---------------------------------------------------------------------------
extern "C" void kernel_launch(void* const* d_in, const int* in_sizes, int n_in,
                              void* d_out, int out_size, void* d_ws, size_t ws_size,
                              hipStream_t stream) {
    const float* x         = (const float*)d_in[0];
    const float* residual  = (const float*)d_in[1];
    const float* norm_w    = (const float*)d_in[2];
    const float* in_proj_w = (const float*)d_in[3];
    const float* conv_w    = (const float*)d_in[4];
    const float* conv_b    = (const float*)d_in[5];
    const float* x_proj_w  = (const float*)d_in[6];
    const float* dt_proj_w = (const float*)d_in[7];
    const float* dt_proj_b = (const float*)d_in[8];
    const float* A_log     = (const float*)d_in[9];
    const float* Dp        = (const float*)d_in[10];
    const float* ln_w      = (const float*)d_in[11];
    const float* ln_b      = (const float*)d_in[12];
    const float* out_proj_w= (const float*)d_in[13];

    float* out = (float*)d_out;                               // (B,L,DM)
    float* res_out = out + (size_t)BATCH * LSEQ * DMQ;        // (B,L,DM)

    const int ROWS = BATCH * LSEQ;  // 4096
    float* xz   = (float*)d_ws;                         // ROWS * 3072
    float* xn   = xz + (size_t)ROWS * 2 * DIQ;          // ROWS * 768 slot
    float* u    = xn + (size_t)ROWS * DMQ;              // ROWS * 1536
    float* dl   = u  + (size_t)ROWS * DIQ;              // ROWS * 1536 (delta -> gate)
    float* yb   = dl + (size_t)ROWS * DIQ;              // ROWS * 1536
    float* xdbl = xn;                                   // ROWS * 80 (front of xn slot)
    // scan temporaries live in the unused tail of the xn slot:
    const size_t SCN = (size_t)BATCH * CCH * DIQ * NST;  // 786432 floats each
    float* hend   = xn + (size_t)ROWS * KDIM;            // +327680
    float* Pp     = hend + SCN;
    float* Hstart = Pp + SCN;                            // ends at 2686976 < ROWS*DMQ... (fits d_ws)
    float* gate = dl;

    // K1: add + RMSNorm
    rmsnorm_k<<<ROWS, 256, 0, stream>>>(x, residual, norm_w, res_out, xn);

    // K2: xz = xn @ in_proj_w   (4096 x 3072 x 768)
    {
        dim3 g(2 * DIQ / 128, ROWS / 128);
        gemm_t<128, 128, 0><<<g, 256, 0, stream>>>(xn, in_proj_w, nullptr, xz,
                                                   DMQ, DMQ, 2 * DIQ, 2 * DIQ);
    }

    // K3: depthwise conv + bias + silu -> u
    conv_silu_k<<<ROWS * (DIQ / 4) / 256, 256, 0, stream>>>(xz, conv_w, conv_b, u);

    // K4: x_dbl = u @ x_proj_w   (4096 x 80 x 1536)
    {
        dim3 g((KDIM + 63) / 64, ROWS / 64);
        gemm64<false, 0><<<g, 256, 0, stream>>>(u, x_proj_w, nullptr, xdbl,
                                                ROWS, KDIM, DIQ, DIQ, KDIM, KDIM);
    }

    // K5: delta = softplus(dts @ dt_proj_w^T + dt_proj_b)   (4096 x 1536 x 48)
    {
        dim3 g(DIQ / 64, ROWS / 64);
        gemm64<true, 1><<<g, 256, 0, stream>>>(xdbl, dt_proj_w, dt_proj_b, dl,
                                               ROWS, DIQ, RR, KDIM, RR, DIQ);
    }

    // K6: chunked selective scan -> yb
    {
        int ngrp = DIQ / 4;  // 384
        scan1_k<<<BATCH * CCH * ngrp, 64, 0, stream>>>(dl, u, xdbl, A_log, hend, Pp);
        scan_combine_k<<<BATCH * ngrp, 64, 0, stream>>>(hend, Pp, Hstart);
        scan3_k<<<BATCH * CCH * ngrp, 64, 0, stream>>>(dl, u, xdbl, A_log, Dp, Hstart, yb);
    }

    // K7: layernorm + silu(z) gate
    lngate_k<<<ROWS, 256, 0, stream>>>(yb, xz, ln_w, ln_b, gate);

    // K8: out = gate @ out_proj_w   (4096 x 768 x 1536)
    {
        dim3 g(DMQ / 64, ROWS / 128);
        gemm_t<128, 64, 0><<<g, 256, 0, stream>>>(gate, out_proj_w, nullptr, out,
                                                  DIQ, DIQ, DMQ, DMQ);
    }
}

// Round 8
// 659.788 us; speedup vs baseline: 2.1124x; 1.3474x over previous
//
#include <hip/hip_runtime.h>
#include <math.h>

#define DMQ 768
#define DIQ 1536
#define LSEQ 2048
#define BATCH 2
#define NST 16
#define RR 48
#define KDIM 80   // R + 2N
#define EPSQ 1e-5f
#define CCH 16    // scan chunks
#define TCH 128   // chunk length (LSEQ / CCH)

typedef __attribute__((ext_vector_type(8))) short short8;
typedef __attribute__((ext_vector_type(4))) float f32x4;

static __device__ __forceinline__ float silu_f(float x) {
    return x / (1.f + __expf(-x));
}
static __device__ __forceinline__ float softplus_f(float x) {
    return (x > 20.f) ? x : log1pf(__expf(x));
}
// bf16 round-to-nearest-even split helpers
static __device__ __forceinline__ ushort f2bf(float v) {
    union { float f; unsigned u; } x; x.f = v;
    unsigned r = x.u + 0x7fffu + ((x.u >> 16) & 1u);
    return (ushort)(r >> 16);
}
static __device__ __forceinline__ float bf2f(ushort h) {
    union { float f; unsigned u; } x; x.u = ((unsigned)h) << 16;
    return x.f;
}

// ---------------------------------------------------------------------------
// K1: residual = x + residual ; xn = rmsnorm(residual)*norm_w -> bf16 hi/lo
// ---------------------------------------------------------------------------
__launch_bounds__(256)
__global__ void rmsnorm_k(const float* __restrict__ x, const float* __restrict__ res,
                          const float* __restrict__ w, float* __restrict__ res_out,
                          ushort* __restrict__ xnH, ushort* __restrict__ xnL) {
    int row = blockIdx.x;
    int tid = threadIdx.x;
    size_t base = (size_t)row * DMQ;
    float v[3];
    float ss = 0.f;
#pragma unroll
    for (int i = 0; i < 3; ++i) {
        int c = tid + i * 256;
        float r = x[base + c] + res[base + c];
        v[i] = r;
        ss = fmaf(r, r, ss);
        res_out[base + c] = r;
    }
#pragma unroll
    for (int off = 1; off < 64; off <<= 1) ss += __shfl_xor(ss, off);
    __shared__ float sbuf[4];
    if ((tid & 63) == 0) sbuf[tid >> 6] = ss;
    __syncthreads();
    float tot = sbuf[0] + sbuf[1] + sbuf[2] + sbuf[3];
    float inv = rsqrtf(tot / (float)DMQ + EPSQ);
#pragma unroll
    for (int i = 0; i < 3; ++i) {
        int c = tid + i * 256;
        float xv = v[i] * inv * w[c];
        ushort hi = f2bf(xv);
        xnH[base + c] = hi;
        xnL[base + c] = f2bf(xv - bf2f(hi));
    }
}

// ---------------------------------------------------------------------------
// Weight transpose + bf16 split: W[K][N] fp32 -> Whi/Wlo [N][K] bf16
// grid (N/32, K/32), 256 threads
// ---------------------------------------------------------------------------
__launch_bounds__(256)
__global__ void wcvt_k(const float* __restrict__ W, ushort* __restrict__ Whi,
                       ushort* __restrict__ Wlo, int K, int N) {
    __shared__ float tile[32][33];
    int n0 = blockIdx.x * 32, k0 = blockIdx.y * 32;
    int t = threadIdx.x;
#pragma unroll
    for (int i = 0; i < 4; ++i) {
        int idx = t + i * 256;
        int r = idx >> 5, c = idx & 31;
        tile[r][c] = W[(size_t)(k0 + r) * N + n0 + c];
    }
    __syncthreads();
#pragma unroll
    for (int i = 0; i < 4; ++i) {
        int idx = t + i * 256;
        int r = idx >> 5, c = idx & 31;   // out row n0+r, col k0+c
        float v = tile[c][r];
        ushort hi = f2bf(v);
        size_t o = (size_t)(n0 + r) * K + k0 + c;
        Whi[o] = hi;
        Wlo[o] = f2bf(v - bf2f(hi));
    }
}

// ---------------------------------------------------------------------------
// Split-bf16 MFMA GEMM: C[M,N] fp32 = (Ah+Al)[M,K] @ (Bh+Bl)[N,K]^T
// (3 MFMA passes: hh + hl + lh; error ~2^-18 relative)
// 128x128 tile, BK=64, 256 threads = 4 waves (2x2), each wave 64x64 = 4x4 frags.
// PK=72: row stride 144 B -> bank index advances by 4 per row, <=2-way conflict
// on ds_read_b128 (free per m136). PK MUST be >= BK=64 (Round-6 bug: PK=40
// overflowed rows into each other -> absmax 1.56).
// Requires M%128==0, N%128==0, K%64==0.
// ---------------------------------------------------------------------------
__launch_bounds__(256)
__global__ void gemm_bf3(const ushort* __restrict__ Ah, const ushort* __restrict__ Al,
                         const ushort* __restrict__ Bh, const ushort* __restrict__ Bl,
                         float* __restrict__ C, int K, int ldc) {
    constexpr int PK = 72;
    __shared__ ushort lAh[128 * PK], lAl[128 * PK], lBh[128 * PK], lBl[128 * PK];
    const int t = threadIdx.x;
    const int bm = blockIdx.y * 128, bn = blockIdx.x * 128;
    const int lane = t & 63;
    const int wr = ((t >> 6) >> 1) * 64, wc = ((t >> 6) & 1) * 64;
    const int lr = lane & 15, lk = (lane >> 4) * 8;
    const int sr = t >> 3, sc = (t & 7) * 8;
    f32x4 acc[4][4] = {};
    for (int k0 = 0; k0 < K; k0 += 64) {
#pragma unroll
        for (int r = 0; r < 4; ++r) {
            int row = r * 32 + sr;
            size_t ga = (size_t)(bm + row) * K + k0 + sc;
            size_t gb = (size_t)(bn + row) * K + k0 + sc;
            int lo = row * PK + sc;
            *(short8*)&lAh[lo] = *(const short8*)&Ah[ga];
            *(short8*)&lAl[lo] = *(const short8*)&Al[ga];
            *(short8*)&lBh[lo] = *(const short8*)&Bh[gb];
            *(short8*)&lBl[lo] = *(const short8*)&Bl[gb];
        }
        __syncthreads();
#pragma unroll
        for (int kf = 0; kf < 2; ++kf) {
            int ko = kf * 32 + lk;
            short8 ah[4], al[4], bh[4], bl[4];
#pragma unroll
            for (int m = 0; m < 4; ++m) {
                int ro = (wr + m * 16 + lr) * PK + ko;
                ah[m] = *(const short8*)&lAh[ro];
                al[m] = *(const short8*)&lAl[ro];
            }
#pragma unroll
            for (int n = 0; n < 4; ++n) {
                int ro = (wc + n * 16 + lr) * PK + ko;
                bh[n] = *(const short8*)&lBh[ro];
                bl[n] = *(const short8*)&lBl[ro];
            }
#pragma unroll
            for (int m = 0; m < 4; ++m)
#pragma unroll
                for (int n = 0; n < 4; ++n) {
                    acc[m][n] = __builtin_amdgcn_mfma_f32_16x16x32_bf16(ah[m], bh[n], acc[m][n], 0, 0, 0);
                    acc[m][n] = __builtin_amdgcn_mfma_f32_16x16x32_bf16(ah[m], bl[n], acc[m][n], 0, 0, 0);
                    acc[m][n] = __builtin_amdgcn_mfma_f32_16x16x32_bf16(al[m], bh[n], acc[m][n], 0, 0, 0);
                }
        }
        __syncthreads();
    }
    // epilogue: C/D layout col=lane&15, row=(lane>>4)*4+j  [verified m89/m91]
#pragma unroll
    for (int m = 0; m < 4; ++m) {
        int r0 = bm + wr + m * 16 + (lane >> 4) * 4;
#pragma unroll
        for (int n = 0; n < 4; ++n) {
            int cc = bn + wc + n * 16 + lr;
#pragma unroll
            for (int j = 0; j < 4; ++j)
                C[(size_t)(r0 + j) * ldc + cc] = acc[m][n][j];
        }
    }
}

// ---------------------------------------------------------------------------
// Legacy fp32 64x64 GEMM for the small-N cases (x_proj, dt_proj).
// ---------------------------------------------------------------------------
template <bool BT, int EPI>
__launch_bounds__(256)
__global__ void gemm64(const float* __restrict__ A, const float* __restrict__ B,
                       const float* __restrict__ bias, float* __restrict__ C,
                       int M, int N, int K, int lda, int ldb, int ldc) {
    constexpr int BM = 64, BN = 64, BK = 16;
    __shared__ float As[BK][BM + 4];
    __shared__ float Bs[BK][BN + 4];
    const int tid = threadIdx.x;
    const int tx = tid & 15, ty = tid >> 4;
    const int bm = blockIdx.y * BM;
    const int bn = blockIdx.x * BN;
    float acc[4][4] = {};
    for (int k0 = 0; k0 < K; k0 += BK) {
#pragma unroll
        for (int i = 0; i < 4; ++i) {
            int t = tid + i * 256;
            int m = t >> 4;
            int kk = t & 15;
            As[kk][m] = A[(size_t)(bm + m) * lda + k0 + kk];
        }
#pragma unroll
        for (int i = 0; i < 4; ++i) {
            int t = tid + i * 256;
            if (!BT) {
                int kk = t >> 6;
                int n = t & 63;
                float v = 0.f;
                if (bn + n < N) v = B[(size_t)(k0 + kk) * ldb + bn + n];
                Bs[kk][n] = v;
            } else {
                int n = t >> 4;
                int kk = t & 15;
                float v = 0.f;
                if (bn + n < N) v = B[(size_t)(bn + n) * ldb + k0 + kk];
                Bs[kk][n] = v;
            }
        }
        __syncthreads();
#pragma unroll
        for (int kk = 0; kk < BK; ++kk) {
            float4 av = *(const float4*)&As[kk][ty * 4];
            float4 bv = *(const float4*)&Bs[kk][tx * 4];
            float a[4] = {av.x, av.y, av.z, av.w};
            float b[4] = {bv.x, bv.y, bv.z, bv.w};
#pragma unroll
            for (int i = 0; i < 4; ++i)
#pragma unroll
                for (int j = 0; j < 4; ++j)
                    acc[i][j] = fmaf(a[i], b[j], acc[i][j]);
        }
        __syncthreads();
    }
#pragma unroll
    for (int i = 0; i < 4; ++i) {
        int m = bm + ty * 4 + i;
#pragma unroll
        for (int j = 0; j < 4; ++j) {
            int n = bn + tx * 4 + j;
            if (n < N) {
                float v = acc[i][j];
                if (EPI == 1) v = softplus_f(v + bias[n]);
                C[(size_t)m * ldc + n] = v;
            }
        }
    }
}

// ---------------------------------------------------------------------------
// K3: depthwise causal-padded conv (kernel 3, pad 1) + bias + silu
// input xc: compact [B*L][DI]
// ---------------------------------------------------------------------------
__launch_bounds__(256)
__global__ void conv_silu_k(const float* __restrict__ xc, const float* __restrict__ cw,
                            const float* __restrict__ cb, float* __restrict__ u) {
    int idx = blockIdx.x * 256 + threadIdx.x;
    const int nd4 = DIQ / 4;
    int row = idx / nd4;
    int d = (idx - row * nd4) * 4;
    int l = row & (LSEQ - 1);
    const float* p = xc + (size_t)row * DIQ + d;
    float a0[4] = {0.f, 0.f, 0.f, 0.f};
    float a1[4];
    float a2[4] = {0.f, 0.f, 0.f, 0.f};
    *(float4*)a1 = *(const float4*)p;
    if (l > 0) *(float4*)a0 = *(const float4*)(p - DIQ);
    if (l < LSEQ - 1) *(float4*)a2 = *(const float4*)(p + DIQ);
    float4 ov;
    float* o = (float*)&ov;
#pragma unroll
    for (int j = 0; j < 4; ++j) {
        float s = cb[d + j];
        s = fmaf(a0[j], cw[(d + j) * 3 + 0], s);
        s = fmaf(a1[j], cw[(d + j) * 3 + 1], s);
        s = fmaf(a2[j], cw[(d + j) * 3 + 2], s);
        o[j] = silu_f(s);
    }
    *(float4*)(u + (size_t)row * DIQ + d) = ov;
}

// ---------------------------------------------------------------------------
// Chunked selective scan (pass1 / combine(in-place Pp->Hstart) / pass3)
// ---------------------------------------------------------------------------
__launch_bounds__(64)
__global__ void scan1_k(const float* __restrict__ delta, const float* __restrict__ u,
                        const float* __restrict__ xdbl, const float* __restrict__ Alog,
                        float* __restrict__ hend, float* __restrict__ Pp) {
    const int ngrp = DIQ / 4;
    int blk = blockIdx.x;
    int dg = blk % ngrp;
    int c = (blk / ngrp) % CCH;
    int b = blk / (ngrp * CCH);
    int d = dg * 4 + (threadIdx.x >> 4);
    int n = threadIdx.x & 15;
    float a = -__expf(Alog[d * NST + n]);
    size_t r0 = (size_t)b * LSEQ + (size_t)c * TCH;
    const float* pd = delta + r0 * DIQ + d;
    const float* pu = u + r0 * DIQ + d;
    const float* pb = xdbl + r0 * KDIM + RR + n;
    float h = 0.f, P = 1.f;
    float dlt = *pd, uu = *pu, bv = *pb;
    for (int t = 0; t < TCH; ++t) {
        float dlt_n = 0.f, uu_n = 0.f, bv_n = 0.f;
        if (t + 1 < TCH) {
            pd += DIQ; pu += DIQ; pb += KDIM;
            dlt_n = *pd; uu_n = *pu; bv_n = *pb;
        }
        float dA = __expf(dlt * a);
        h = fmaf(dA, h, dlt * uu * bv);
        P *= dA;
        dlt = dlt_n; uu = uu_n; bv = bv_n;
    }
    size_t idx = (((size_t)b * CCH + c) * DIQ + d) * NST + n;
    hend[idx] = h;
    Pp[idx] = P;
}

__launch_bounds__(64)
__global__ void scan_combine_k(const float* __restrict__ hend, float* __restrict__ PpH) {
    const int ngrp = DIQ / 4;
    int blk = blockIdx.x;
    int b = blk / ngrp;
    int dg = blk % ngrp;
    int d = dg * 4 + (threadIdx.x >> 4);
    int n = threadIdx.x & 15;
    size_t base = ((size_t)b * CCH) * DIQ * NST + (size_t)d * NST + n;
    const size_t cs = (size_t)DIQ * NST;
    float H = 0.f;
#pragma unroll
    for (int c = 0; c < CCH; ++c) {
        size_t o = base + c * cs;
        float P = PpH[o];
        PpH[o] = H;                 // Hstart (in-place over Pp)
        H = fmaf(P, H, hend[o]);
    }
}

__launch_bounds__(64)
__global__ void scan3_k(const float* __restrict__ delta, const float* __restrict__ u,
                        const float* __restrict__ xdbl, const float* __restrict__ Alog,
                        const float* __restrict__ Dp, const float* __restrict__ Hstart,
                        float* __restrict__ y) {
    const int ngrp = DIQ / 4;
    int blk = blockIdx.x;
    int dg = blk % ngrp;
    int c = (blk / ngrp) % CCH;
    int b = blk / (ngrp * CCH);
    int d = dg * 4 + (threadIdx.x >> 4);
    int n = threadIdx.x & 15;
    float a = -__expf(Alog[d * NST + n]);
    float Dd = Dp[d];
    size_t idx = (((size_t)b * CCH + c) * DIQ + d) * NST + n;
    float h = Hstart[idx];
    size_t r0 = (size_t)b * LSEQ + (size_t)c * TCH;
    const float* pd = delta + r0 * DIQ + d;
    const float* pu = u + r0 * DIQ + d;
    const float* pb = xdbl + r0 * KDIM + RR + n;
    const float* pc = xdbl + r0 * KDIM + RR + NST + n;
    float* py = y + r0 * DIQ + d;
    float dlt = *pd, uu = *pu, bv = *pb, cv = *pc;
    for (int t = 0; t < TCH; ++t) {
        float dlt_n = 0.f, uu_n = 0.f, bv_n = 0.f, cv_n = 0.f;
        if (t + 1 < TCH) {
            pd += DIQ; pu += DIQ; pb += KDIM; pc += KDIM;
            dlt_n = *pd; uu_n = *pu; bv_n = *pb; cv_n = *pc;
        }
        float dA = __expf(dlt * a);
        h = fmaf(dA, h, dlt * uu * bv);
        float yc = h * cv;
        yc += __shfl_xor(yc, 1);
        yc += __shfl_xor(yc, 2);
        yc += __shfl_xor(yc, 4);
        yc += __shfl_xor(yc, 8);
        if (n == 0) py[(size_t)t * DIQ] = fmaf(uu, Dd, yc);
        dlt = dlt_n; uu = uu_n; bv = bv_n; cv = cv_n;
    }
}

// ---------------------------------------------------------------------------
// K7: layernorm(y)*ln_w+ln_b, gated by silu(z) -> bf16 hi/lo
// z is compact [B*L][DI]
// ---------------------------------------------------------------------------
__launch_bounds__(256)
__global__ void lngate_k(const float* __restrict__ y, const float* __restrict__ z,
                         const float* __restrict__ lw, const float* __restrict__ lb,
                         ushort* __restrict__ gH, ushort* __restrict__ gL) {
    int row = blockIdx.x;
    int tid = threadIdx.x;
    size_t ybase = (size_t)row * DIQ;
    float v[6];
    float s = 0.f, sq = 0.f;
#pragma unroll
    for (int i = 0; i < 6; ++i) {
        int c = tid + i * 256;
        float t = y[ybase + c];
        v[i] = t;
        s += t;
        sq = fmaf(t, t, sq);
    }
#pragma unroll
    for (int off = 1; off < 64; off <<= 1) {
        s += __shfl_xor(s, off);
        sq += __shfl_xor(sq, off);
    }
    __shared__ float ssb[4], sqb[4];
    if ((tid & 63) == 0) {
        ssb[tid >> 6] = s;
        sqb[tid >> 6] = sq;
    }
    __syncthreads();
    s = ssb[0] + ssb[1] + ssb[2] + ssb[3];
    sq = sqb[0] + sqb[1] + sqb[2] + sqb[3];
    float mu = s / (float)DIQ;
    float var = sq / (float)DIQ - mu * mu;
    float inv = rsqrtf(var + EPSQ);
#pragma unroll
    for (int i = 0; i < 6; ++i) {
        int c = tid + i * 256;
        float t = (v[i] - mu) * inv * lw[c] + lb[c];
        float g = t * silu_f(z[ybase + c]);
        ushort hi = f2bf(g);
        gH[ybase + c] = hi;
        gL[ybase + c] = f2bf(g - bf2f(hi));
    }
}

// ---------------------------------------------------------------------------
extern "C" void kernel_launch(void* const* d_in, const int* in_sizes, int n_in,
                              void* d_out, int out_size, void* d_ws, size_t ws_size,
                              hipStream_t stream) {
    const float* x         = (const float*)d_in[0];
    const float* residual  = (const float*)d_in[1];
    const float* norm_w    = (const float*)d_in[2];
    const float* in_proj_w = (const float*)d_in[3];
    const float* conv_w    = (const float*)d_in[4];
    const float* conv_b    = (const float*)d_in[5];
    const float* x_proj_w  = (const float*)d_in[6];
    const float* dt_proj_w = (const float*)d_in[7];
    const float* dt_proj_b = (const float*)d_in[8];
    const float* A_log     = (const float*)d_in[9];
    const float* Dp        = (const float*)d_in[10];
    const float* ln_w      = (const float*)d_in[11];
    const float* ln_b      = (const float*)d_in[12];
    const float* out_proj_w= (const float*)d_in[13];

    float* out = (float*)d_out;                               // (B,L,DM)
    float* res_out = out + (size_t)BATCH * LSEQ * DMQ;        // (B,L,DM)

    const int ROWS = BATCH * LSEQ;                 // 4096
    const size_t RF = (size_t)ROWS * DIQ;          // 6291456
    const size_t SCN = (size_t)BATCH * CCH * DIQ * NST;  // 786432

    float* bufA = (float*)d_ws;          // xc (K2-K3), then y (K6-K7)
    float* bufZ = bufA + RF;             // z (K2-K7)
    float* bufU = bufZ + RF;             // u
    float* bufD = bufU + RF;             // delta
    float* xdbl = bufD + RF;             // ROWS*KDIM
    float* hend = xdbl + (size_t)ROWS * KDIM;
    float* PpH  = hend + SCN;            // Pp, then Hstart in-place
    ushort* WoutH = (ushort*)(PpH + SCN);
    ushort* WoutL = WoutH + (size_t)DMQ * DIQ;     // 768*1536
    ushort* Rbase = WoutL + (size_t)DMQ * DIQ;
    // early use of R: xn hi/lo + Win hi/lo ; late use: gate hi/lo
    ushort* xnH  = Rbase;
    ushort* xnL  = xnH + (size_t)ROWS * DMQ;
    ushort* WinH = xnL + (size_t)ROWS * DMQ;
    ushort* WinL = WinH + (size_t)DMQ * 2 * DIQ;   // 768*3072
    ushort* gateH = Rbase;
    ushort* gateL = gateH + (size_t)ROWS * DIQ;

    // weight conversion (every launch; ws is re-poisoned each call)
    wcvt_k<<<dim3(2 * DIQ / 32, DMQ / 32), 256, 0, stream>>>(in_proj_w, WinH, WinL, DMQ, 2 * DIQ);
    wcvt_k<<<dim3(DMQ / 32, DIQ / 32), 256, 0, stream>>>(out_proj_w, WoutH, WoutL, DIQ, DMQ);

    // K1: add + RMSNorm -> xn hi/lo
    rmsnorm_k<<<ROWS, 256, 0, stream>>>(x, residual, norm_w, res_out, xnH, xnL);

    // K2: xc = xn @ Win[:, :DI] ; z = xn @ Win[:, DI:]
    {
        dim3 g(DIQ / 128, ROWS / 128);  // 12 x 32
        gemm_bf3<<<g, 256, 0, stream>>>(xnH, xnL, WinH, WinL, bufA, DMQ, DIQ);
        size_t off = (size_t)DIQ * DMQ;
        gemm_bf3<<<g, 256, 0, stream>>>(xnH, xnL, WinH + off, WinL + off, bufZ, DMQ, DIQ);
    }

    // K3: depthwise conv + bias + silu -> u
    conv_silu_k<<<ROWS * (DIQ / 4) / 256, 256, 0, stream>>>(bufA, conv_w, conv_b, bufU);

    // K4: x_dbl = u @ x_proj_w   (4096 x 80 x 1536, fp32)
    {
        dim3 g((KDIM + 63) / 64, ROWS / 64);
        gemm64<false, 0><<<g, 256, 0, stream>>>(bufU, x_proj_w, nullptr, xdbl,
                                                ROWS, KDIM, DIQ, DIQ, KDIM, KDIM);
    }

    // K5: delta = softplus(dts @ dt_proj_w^T + dt_proj_b)   (fp32)
    {
        dim3 g(DIQ / 64, ROWS / 64);
        gemm64<true, 1><<<g, 256, 0, stream>>>(xdbl, dt_proj_w, dt_proj_b, bufD,
                                               ROWS, DIQ, RR, KDIM, RR, DIQ);
    }

    // K6: chunked selective scan -> y (bufA reused)
    {
        int ngrp = DIQ / 4;
        scan1_k<<<BATCH * CCH * ngrp, 64, 0, stream>>>(bufD, bufU, xdbl, A_log, hend, PpH);
        scan_combine_k<<<BATCH * ngrp, 64, 0, stream>>>(hend, PpH);
        scan3_k<<<BATCH * CCH * ngrp, 64, 0, stream>>>(bufD, bufU, xdbl, A_log, Dp, PpH, bufA);
    }

    // K7: layernorm + silu(z) gate -> gate hi/lo
    lngate_k<<<ROWS, 256, 0, stream>>>(bufA, bufZ, ln_w, ln_b, gateH, gateL);

    // K8: out = gate @ Wout   (4096 x 768, K=1536)
    {
        dim3 g(DMQ / 128, ROWS / 128);  // 6 x 32
        gemm_bf3<<<g, 256, 0, stream>>>(gateH, gateL, WoutH, WoutL, out, DIQ, DMQ);
    }
}

// Round 13
// 563.758 us; speedup vs baseline: 2.4722x; 1.1703x over previous
//
#include <hip/hip_runtime.h>
#include <math.h>

#define DMQ 768
#define DIQ 1536
#define LSEQ 2048
#define BATCH 2
#define NST 16
#define RR 48
#define KDIM 80   // R + 2N
#define EPSQ 1e-5f
#define CCH 16    // scan chunks
#define TCH 128   // chunk length (LSEQ / CCH)

typedef __attribute__((ext_vector_type(8))) short short8;
typedef __attribute__((ext_vector_type(4))) float f32x4;

static __device__ __forceinline__ float silu_f(float x) {
    return x / (1.f + __expf(-x));
}
static __device__ __forceinline__ float softplus_f(float x) {
    return (x > 20.f) ? x : log1pf(__expf(x));
}
// bf16 round-to-nearest-even split helpers
static __device__ __forceinline__ ushort f2bf(float v) {
    union { float f; unsigned u; } x; x.f = v;
    unsigned r = x.u + 0x7fffu + ((x.u >> 16) & 1u);
    return (ushort)(r >> 16);
}
static __device__ __forceinline__ float bf2f(ushort h) {
    union { float f; unsigned u; } x; x.u = ((unsigned)h) << 16;
    return x.f;
}

// ---------------------------------------------------------------------------
// K1: residual = x + residual ; xn = rmsnorm(residual)*norm_w -> bf16 hi/lo
// ---------------------------------------------------------------------------
__launch_bounds__(256)
__global__ void rmsnorm_k(const float* __restrict__ x, const float* __restrict__ res,
                          const float* __restrict__ w, float* __restrict__ res_out,
                          ushort* __restrict__ xnH, ushort* __restrict__ xnL) {
    int row = blockIdx.x;
    int tid = threadIdx.x;
    size_t base = (size_t)row * DMQ;
    float v[3];
    float ss = 0.f;
#pragma unroll
    for (int i = 0; i < 3; ++i) {
        int c = tid + i * 256;
        float r = x[base + c] + res[base + c];
        v[i] = r;
        ss = fmaf(r, r, ss);
        res_out[base + c] = r;
    }
#pragma unroll
    for (int off = 1; off < 64; off <<= 1) ss += __shfl_xor(ss, off);
    __shared__ float sbuf[4];
    if ((tid & 63) == 0) sbuf[tid >> 6] = ss;
    __syncthreads();
    float tot = sbuf[0] + sbuf[1] + sbuf[2] + sbuf[3];
    float inv = rsqrtf(tot / (float)DMQ + EPSQ);
#pragma unroll
    for (int i = 0; i < 3; ++i) {
        int c = tid + i * 256;
        float xv = v[i] * inv * w[c];
        ushort hi = f2bf(xv);
        xnH[base + c] = hi;
        xnL[base + c] = f2bf(xv - bf2f(hi));
    }
}

// ---------------------------------------------------------------------------
// Weight transpose + bf16 split: W[K][N] fp32 -> Whi/Wlo [N][K] bf16
// grid (N/32, K/32), 256 threads
// ---------------------------------------------------------------------------
__launch_bounds__(256)
__global__ void wcvt_k(const float* __restrict__ W, ushort* __restrict__ Whi,
                       ushort* __restrict__ Wlo, int K, int N) {
    __shared__ float tile[32][33];
    int n0 = blockIdx.x * 32, k0 = blockIdx.y * 32;
    int t = threadIdx.x;
#pragma unroll
    for (int i = 0; i < 4; ++i) {
        int idx = t + i * 256;
        int r = idx >> 5, c = idx & 31;
        tile[r][c] = W[(size_t)(k0 + r) * N + n0 + c];
    }
    __syncthreads();
#pragma unroll
    for (int i = 0; i < 4; ++i) {
        int idx = t + i * 256;
        int r = idx >> 5, c = idx & 31;   // out row n0+r, col k0+c
        float v = tile[c][r];
        ushort hi = f2bf(v);
        size_t o = (size_t)(n0 + r) * K + k0 + c;
        Whi[o] = hi;
        Wlo[o] = f2bf(v - bf2f(hi));
    }
}

// ---------------------------------------------------------------------------
// Split-bf16 MFMA GEMM: C[M,N] fp32 = (Ah+Al)[M,K] @ (Bh+Bl)[N,K]^T
// PK=72 (>= BK=64; Round-6 bug was PK=40 overflow). 128x128 tile, BK=64,
// 4 waves (2x2), each wave 64x64 = 4x4 frags of 16x16x32.
// ---------------------------------------------------------------------------
__launch_bounds__(256)
__global__ void gemm_bf3(const ushort* __restrict__ Ah, const ushort* __restrict__ Al,
                         const ushort* __restrict__ Bh, const ushort* __restrict__ Bl,
                         float* __restrict__ C, int K, int ldc) {
    constexpr int PK = 72;
    __shared__ ushort lAh[128 * PK], lAl[128 * PK], lBh[128 * PK], lBl[128 * PK];
    const int t = threadIdx.x;
    const int bm = blockIdx.y * 128, bn = blockIdx.x * 128;
    const int lane = t & 63;
    const int wr = ((t >> 6) >> 1) * 64, wc = ((t >> 6) & 1) * 64;
    const int lr = lane & 15, lk = (lane >> 4) * 8;
    const int sr = t >> 3, sc = (t & 7) * 8;
    f32x4 acc[4][4] = {};
    for (int k0 = 0; k0 < K; k0 += 64) {
#pragma unroll
        for (int r = 0; r < 4; ++r) {
            int row = r * 32 + sr;
            size_t ga = (size_t)(bm + row) * K + k0 + sc;
            size_t gb = (size_t)(bn + row) * K + k0 + sc;
            int lo = row * PK + sc;
            *(short8*)&lAh[lo] = *(const short8*)&Ah[ga];
            *(short8*)&lAl[lo] = *(const short8*)&Al[ga];
            *(short8*)&lBh[lo] = *(const short8*)&Bh[gb];
            *(short8*)&lBl[lo] = *(const short8*)&Bl[gb];
        }
        __syncthreads();
#pragma unroll
        for (int kf = 0; kf < 2; ++kf) {
            int ko = kf * 32 + lk;
            short8 ah[4], al[4], bh[4], bl[4];
#pragma unroll
            for (int m = 0; m < 4; ++m) {
                int ro = (wr + m * 16 + lr) * PK + ko;
                ah[m] = *(const short8*)&lAh[ro];
                al[m] = *(const short8*)&lAl[ro];
            }
#pragma unroll
            for (int n = 0; n < 4; ++n) {
                int ro = (wc + n * 16 + lr) * PK + ko;
                bh[n] = *(const short8*)&lBh[ro];
                bl[n] = *(const short8*)&lBl[ro];
            }
#pragma unroll
            for (int m = 0; m < 4; ++m)
#pragma unroll
                for (int n = 0; n < 4; ++n) {
                    acc[m][n] = __builtin_amdgcn_mfma_f32_16x16x32_bf16(ah[m], bh[n], acc[m][n], 0, 0, 0);
                    acc[m][n] = __builtin_amdgcn_mfma_f32_16x16x32_bf16(ah[m], bl[n], acc[m][n], 0, 0, 0);
                    acc[m][n] = __builtin_amdgcn_mfma_f32_16x16x32_bf16(al[m], bh[n], acc[m][n], 0, 0, 0);
                }
        }
        __syncthreads();
    }
    // epilogue: C/D layout col=lane&15, row=(lane>>4)*4+j  [verified m89/m91]
#pragma unroll
    for (int m = 0; m < 4; ++m) {
        int r0 = bm + wr + m * 16 + (lane >> 4) * 4;
#pragma unroll
        for (int n = 0; n < 4; ++n) {
            int cc = bn + wc + n * 16 + lr;
#pragma unroll
            for (int j = 0; j < 4; ++j)
                C[(size_t)(r0 + j) * ldc + cc] = acc[m][n][j];
        }
    }
}

// ---------------------------------------------------------------------------
// Legacy fp32 64x64 GEMM (only dt_proj uses it now: BT=true, EPI=1).
// ---------------------------------------------------------------------------
template <bool BT, int EPI>
__launch_bounds__(256)
__global__ void gemm64(const float* __restrict__ A, const float* __restrict__ B,
                       const float* __restrict__ bias, float* __restrict__ C,
                       int M, int N, int K, int lda, int ldb, int ldc) {
    constexpr int BM = 64, BN = 64, BK = 16;
    __shared__ float As[BK][BM + 4];
    __shared__ float Bs[BK][BN + 4];
    const int tid = threadIdx.x;
    const int tx = tid & 15, ty = tid >> 4;
    const int bm = blockIdx.y * BM;
    const int bn = blockIdx.x * BN;
    float acc[4][4] = {};
    for (int k0 = 0; k0 < K; k0 += BK) {
#pragma unroll
        for (int i = 0; i < 4; ++i) {
            int t = tid + i * 256;
            int m = t >> 4;
            int kk = t & 15;
            As[kk][m] = A[(size_t)(bm + m) * lda + k0 + kk];
        }
#pragma unroll
        for (int i = 0; i < 4; ++i) {
            int t = tid + i * 256;
            if (!BT) {
                int kk = t >> 6;
                int n = t & 63;
                float v = 0.f;
                if (bn + n < N) v = B[(size_t)(k0 + kk) * ldb + bn + n];
                Bs[kk][n] = v;
            } else {
                int n = t >> 4;
                int kk = t & 15;
                float v = 0.f;
                if (bn + n < N) v = B[(size_t)(bn + n) * ldb + k0 + kk];
                Bs[kk][n] = v;
            }
        }
        __syncthreads();
#pragma unroll
        for (int kk = 0; kk < BK; ++kk) {
            float4 av = *(const float4*)&As[kk][ty * 4];
            float4 bv = *(const float4*)&Bs[kk][tx * 4];
            float a[4] = {av.x, av.y, av.z, av.w};
            float b[4] = {bv.x, bv.y, bv.z, bv.w};
#pragma unroll
            for (int i = 0; i < 4; ++i)
#pragma unroll
                for (int j = 0; j < 4; ++j)
                    acc[i][j] = fmaf(a[i], b[j], acc[i][j]);
        }
        __syncthreads();
    }
#pragma unroll
    for (int i = 0; i < 4; ++i) {
        int m = bm + ty * 4 + i;
#pragma unroll
        for (int j = 0; j < 4; ++j) {
            int n = bn + tx * 4 + j;
            if (n < N) {
                float v = acc[i][j];
                if (EPI == 1) v = softplus_f(v + bias[n]);
                C[(size_t)m * ldc + n] = v;
            }
        }
    }
}

// ---------------------------------------------------------------------------
// K4 replacement: x_dbl = u @ x_proj_w  (4096 x 80, K=1536), split-K x4.
// Grid (256 M-tiles of 16 rows, 4 K-splits of 384). Block: 256 thr = 4 waves.
// Thread: row = t>>4 (16 rows), cols (t&15)*5 .. +4 (80 cols).
// W chunk staged transposed into LDS wt[80][68] (pad 68: 16B-aligned rows,
// read pattern 2-way bank aliased = free; 4-lane broadcast per col-group).
// Partials -> part[ks][4096][80], reduced by xpred_k.
// Round-8 diagnosis: old gemm64 grid was 128 blocks = 0.5 waves/SIMD,
// Occupancy 5.5%, VALUBusy 7.5% -> pure latency-bound. This gets 4 waves/SIMD.
// ---------------------------------------------------------------------------
__launch_bounds__(256)
__global__ void xp_k(const float* __restrict__ u, const float* __restrict__ xW,
                     float* __restrict__ part) {
    __shared__ float wt[80 * 68];
    const int t = threadIdx.x;
    const int r = blockIdx.x * 16 + (t >> 4);
    const int c0 = (t & 15) * 5;
    const int k0s = blockIdx.y * 384;
    float acc[5] = {0.f, 0.f, 0.f, 0.f, 0.f};
    for (int ch = 0; ch < 6; ++ch) {
        int kc = k0s + ch * 64;
        __syncthreads();
#pragma unroll
        for (int i = 0; i < 20; ++i) {
            int idx = t + i * 256;       // 5120 = 64k x 80c
            int c = idx % 80;
            int k = idx / 80;
            wt[c * 68 + k] = xW[(size_t)(kc + k) * KDIM + c];
        }
        __syncthreads();
        const float4* pa = (const float4*)&u[(size_t)r * DIQ + kc];
#pragma unroll
        for (int i = 0; i < 16; ++i) {
            float4 av = pa[i];
#pragma unroll
            for (int j = 0; j < 5; ++j) {
                float4 wv = *(const float4*)&wt[(c0 + j) * 68 + i * 4];
                acc[j] = fmaf(av.x, wv.x, acc[j]);
                acc[j] = fmaf(av.y, wv.y, acc[j]);
                acc[j] = fmaf(av.z, wv.z, acc[j]);
                acc[j] = fmaf(av.w, wv.w, acc[j]);
            }
        }
    }
    float* po = &part[((size_t)blockIdx.y * 4096 + r) * KDIM + c0];
#pragma unroll
    for (int j = 0; j < 5; ++j) po[j] = acc[j];
}

__launch_bounds__(256)
__global__ void xpred_k(const float* __restrict__ part, float* __restrict__ xdbl) {
    int i = blockIdx.x * 256 + threadIdx.x;      // 81920 float4s
    const int S4 = 4096 * KDIM / 4;              // 81920
    const float4* p = (const float4*)part;
    float4 a = p[i], b = p[i + S4], c = p[i + 2 * S4], d = p[i + 3 * S4];
    float4 o;
    o.x = a.x + b.x + c.x + d.x;
    o.y = a.y + b.y + c.y + d.y;
    o.z = a.z + b.z + c.z + d.z;
    o.w = a.w + b.w + c.w + d.w;
    ((float4*)xdbl)[i] = o;
}

// ---------------------------------------------------------------------------
// K3: depthwise causal-padded conv (kernel 3, pad 1) + bias + silu
// input xc: compact [B*L][DI]
// ---------------------------------------------------------------------------
__launch_bounds__(256)
__global__ void conv_silu_k(const float* __restrict__ xc, const float* __restrict__ cw,
                            const float* __restrict__ cb, float* __restrict__ u) {
    int idx = blockIdx.x * 256 + threadIdx.x;
    const int nd4 = DIQ / 4;
    int row = idx / nd4;
    int d = (idx - row * nd4) * 4;
    int l = row & (LSEQ - 1);
    const float* p = xc + (size_t)row * DIQ + d;
    float a0[4] = {0.f, 0.f, 0.f, 0.f};
    float a1[4];
    float a2[4] = {0.f, 0.f, 0.f, 0.f};
    *(float4*)a1 = *(const float4*)p;
    if (l > 0) *(float4*)a0 = *(const float4*)(p - DIQ);
    if (l < LSEQ - 1) *(float4*)a2 = *(const float4*)(p + DIQ);
    float4 ov;
    float* o = (float*)&ov;
#pragma unroll
    for (int j = 0; j < 4; ++j) {
        float s = cb[d + j];
        s = fmaf(a0[j], cw[(d + j) * 3 + 0], s);
        s = fmaf(a1[j], cw[(d + j) * 3 + 1], s);
        s = fmaf(a2[j], cw[(d + j) * 3 + 2], s);
        o[j] = silu_f(s);
    }
    *(float4*)(u + (size_t)row * DIQ + d) = ov;
}

// ---------------------------------------------------------------------------
// Chunked selective scan (pass1 / combine(in-place Pp->Hstart) / pass3)
// ---------------------------------------------------------------------------
__launch_bounds__(64)
__global__ void scan1_k(const float* __restrict__ delta, const float* __restrict__ u,
                        const float* __restrict__ xdbl, const float* __restrict__ Alog,
                        float* __restrict__ hend, float* __restrict__ Pp) {
    const int ngrp = DIQ / 4;
    int blk = blockIdx.x;
    int dg = blk % ngrp;
    int c = (blk / ngrp) % CCH;
    int b = blk / (ngrp * CCH);
    int d = dg * 4 + (threadIdx.x >> 4);
    int n = threadIdx.x & 15;
    float a = -__expf(Alog[d * NST + n]);
    size_t r0 = (size_t)b * LSEQ + (size_t)c * TCH;
    const float* pd = delta + r0 * DIQ + d;
    const float* pu = u + r0 * DIQ + d;
    const float* pb = xdbl + r0 * KDIM + RR + n;
    float h = 0.f, P = 1.f;
    float dlt = *pd, uu = *pu, bv = *pb;
    for (int t = 0; t < TCH; ++t) {
        float dlt_n = 0.f, uu_n = 0.f, bv_n = 0.f;
        if (t + 1 < TCH) {
            pd += DIQ; pu += DIQ; pb += KDIM;
            dlt_n = *pd; uu_n = *pu; bv_n = *pb;
        }
        float dA = __expf(dlt * a);
        h = fmaf(dA, h, dlt * uu * bv);
        P *= dA;
        dlt = dlt_n; uu = uu_n; bv = bv_n;
    }
    size_t idx = (((size_t)b * CCH + c) * DIQ + d) * NST + n;
    hend[idx] = h;
    Pp[idx] = P;
}

__launch_bounds__(64)
__global__ void scan_combine_k(const float* __restrict__ hend, float* __restrict__ PpH) {
    const int ngrp = DIQ / 4;
    int blk = blockIdx.x;
    int b = blk / ngrp;
    int dg = blk % ngrp;
    int d = dg * 4 + (threadIdx.x >> 4);
    int n = threadIdx.x & 15;
    size_t base = ((size_t)b * CCH) * DIQ * NST + (size_t)d * NST + n;
    const size_t cs = (size_t)DIQ * NST;
    float H = 0.f;
#pragma unroll
    for (int c = 0; c < CCH; ++c) {
        size_t o = base + c * cs;
        float P = PpH[o];
        PpH[o] = H;                 // Hstart (in-place over Pp)
        H = fmaf(P, H, hend[o]);
    }
}

__launch_bounds__(64)
__global__ void scan3_k(const float* __restrict__ delta, const float* __restrict__ u,
                        const float* __restrict__ xdbl, const float* __restrict__ Alog,
                        const float* __restrict__ Dp, const float* __restrict__ Hstart,
                        float* __restrict__ y) {
    const int ngrp = DIQ / 4;
    int blk = blockIdx.x;
    int dg = blk % ngrp;
    int c = (blk / ngrp) % CCH;
    int b = blk / (ngrp * CCH);
    int d = dg * 4 + (threadIdx.x >> 4);
    int n = threadIdx.x & 15;
    float a = -__expf(Alog[d * NST + n]);
    float Dd = Dp[d];
    size_t idx = (((size_t)b * CCH + c) * DIQ + d) * NST + n;
    float h = Hstart[idx];
    size_t r0 = (size_t)b * LSEQ + (size_t)c * TCH;
    const float* pd = delta + r0 * DIQ + d;
    const float* pu = u + r0 * DIQ + d;
    const float* pb = xdbl + r0 * KDIM + RR + n;
    const float* pc = xdbl + r0 * KDIM + RR + NST + n;
    float* py = y + r0 * DIQ + d;
    float dlt = *pd, uu = *pu, bv = *pb, cv = *pc;
    for (int t = 0; t < TCH; ++t) {
        float dlt_n = 0.f, uu_n = 0.f, bv_n = 0.f, cv_n = 0.f;
        if (t + 1 < TCH) {
            pd += DIQ; pu += DIQ; pb += KDIM; pc += KDIM;
            dlt_n = *pd; uu_n = *pu; bv_n = *pb; cv_n = *pc;
        }
        float dA = __expf(dlt * a);
        h = fmaf(dA, h, dlt * uu * bv);
        float yc = h * cv;
        yc += __shfl_xor(yc, 1);
        yc += __shfl_xor(yc, 2);
        yc += __shfl_xor(yc, 4);
        yc += __shfl_xor(yc, 8);
        if (n == 0) py[(size_t)t * DIQ] = fmaf(uu, Dd, yc);
        dlt = dlt_n; uu = uu_n; bv = bv_n; cv = cv_n;
    }
}

// ---------------------------------------------------------------------------
// K7: layernorm(y)*ln_w+ln_b, gated by silu(z) -> bf16 hi/lo
// ---------------------------------------------------------------------------
__launch_bounds__(256)
__global__ void lngate_k(const float* __restrict__ y, const float* __restrict__ z,
                         const float* __restrict__ lw, const float* __restrict__ lb,
                         ushort* __restrict__ gH, ushort* __restrict__ gL) {
    int row = blockIdx.x;
    int tid = threadIdx.x;
    size_t ybase = (size_t)row * DIQ;
    float v[6];
    float s = 0.f, sq = 0.f;
#pragma unroll
    for (int i = 0; i < 6; ++i) {
        int c = tid + i * 256;
        float t = y[ybase + c];
        v[i] = t;
        s += t;
        sq = fmaf(t, t, sq);
    }
#pragma unroll
    for (int off = 1; off < 64; off <<= 1) {
        s += __shfl_xor(s, off);
        sq += __shfl_xor(sq, off);
    }
    __shared__ float ssb[4], sqb[4];
    if ((tid & 63) == 0) {
        ssb[tid >> 6] = s;
        sqb[tid >> 6] = sq;
    }
    __syncthreads();
    s = ssb[0] + ssb[1] + ssb[2] + ssb[3];
    sq = sqb[0] + sqb[1] + sqb[2] + sqb[3];
    float mu = s / (float)DIQ;
    float var = sq / (float)DIQ - mu * mu;
    float inv = rsqrtf(var + EPSQ);
#pragma unroll
    for (int i = 0; i < 6; ++i) {
        int c = tid + i * 256;
        float t = (v[i] - mu) * inv * lw[c] + lb[c];
        float g = t * silu_f(z[ybase + c]);
        ushort hi = f2bf(g);
        gH[ybase + c] = hi;
        gL[ybase + c] = f2bf(g - bf2f(hi));
    }
}

// ---------------------------------------------------------------------------
extern "C" void kernel_launch(void* const* d_in, const int* in_sizes, int n_in,
                              void* d_out, int out_size, void* d_ws, size_t ws_size,
                              hipStream_t stream) {
    const float* x         = (const float*)d_in[0];
    const float* residual  = (const float*)d_in[1];
    const float* norm_w    = (const float*)d_in[2];
    const float* in_proj_w = (const float*)d_in[3];
    const float* conv_w    = (const float*)d_in[4];
    const float* conv_b    = (const float*)d_in[5];
    const float* x_proj_w  = (const float*)d_in[6];
    const float* dt_proj_w = (const float*)d_in[7];
    const float* dt_proj_b = (const float*)d_in[8];
    const float* A_log     = (const float*)d_in[9];
    const float* Dp        = (const float*)d_in[10];
    const float* ln_w      = (const float*)d_in[11];
    const float* ln_b      = (const float*)d_in[12];
    const float* out_proj_w= (const float*)d_in[13];

    float* out = (float*)d_out;                               // (B,L,DM)
    float* res_out = out + (size_t)BATCH * LSEQ * DMQ;        // (B,L,DM)

    const int ROWS = BATCH * LSEQ;                 // 4096
    const size_t RF = (size_t)ROWS * DIQ;          // 6291456
    const size_t SCN = (size_t)BATCH * CCH * DIQ * NST;  // 786432

    float* bufA = (float*)d_ws;          // xc (K2-K3), then y (K6-K7)
    float* bufZ = bufA + RF;             // z (K2-K7)
    float* bufU = bufZ + RF;             // u
    float* bufD = bufU + RF;             // delta
    float* xdbl = bufD + RF;             // ROWS*KDIM
    float* hend = xdbl + (size_t)ROWS * KDIM;
    float* PpH  = hend + SCN;            // Pp, then Hstart in-place
    float* part = hend;                  // xp partials (4*327680 floats) overlap
                                         // hend+PpH (free during x_proj phase)
    ushort* WoutH = (ushort*)(PpH + SCN);
    ushort* WoutL = WoutH + (size_t)DMQ * DIQ;     // 768*1536
    ushort* Rbase = WoutL + (size_t)DMQ * DIQ;
    // early use of R: xn hi/lo + Win hi/lo ; late use: gate hi/lo
    ushort* xnH  = Rbase;
    ushort* xnL  = xnH + (size_t)ROWS * DMQ;
    ushort* WinH = xnL + (size_t)ROWS * DMQ;
    ushort* WinL = WinH + (size_t)DMQ * 2 * DIQ;   // 768*3072
    ushort* gateH = Rbase;
    ushort* gateL = gateH + (size_t)ROWS * DIQ;

    // weight conversion (every launch; ws is re-poisoned each call)
    wcvt_k<<<dim3(2 * DIQ / 32, DMQ / 32), 256, 0, stream>>>(in_proj_w, WinH, WinL, DMQ, 2 * DIQ);
    wcvt_k<<<dim3(DMQ / 32, DIQ / 32), 256, 0, stream>>>(out_proj_w, WoutH, WoutL, DIQ, DMQ);

    // K1: add + RMSNorm -> xn hi/lo
    rmsnorm_k<<<ROWS, 256, 0, stream>>>(x, residual, norm_w, res_out, xnH, xnL);

    // K2: xc = xn @ Win[:, :DI] ; z = xn @ Win[:, DI:]
    {
        dim3 g(DIQ / 128, ROWS / 128);  // 12 x 32
        gemm_bf3<<<g, 256, 0, stream>>>(xnH, xnL, WinH, WinL, bufA, DMQ, DIQ);
        size_t off = (size_t)DIQ * DMQ;
        gemm_bf3<<<g, 256, 0, stream>>>(xnH, xnL, WinH + off, WinL + off, bufZ, DMQ, DIQ);
    }

    // K3: depthwise conv + bias + silu -> u
    conv_silu_k<<<ROWS * (DIQ / 4) / 256, 256, 0, stream>>>(bufA, conv_w, conv_b, bufU);

    // K4: x_dbl = u @ x_proj_w  (split-K x4 + reduce)
    {
        dim3 g(ROWS / 16, 4);           // 256 x 4 = 1024 blocks
        xp_k<<<g, 256, 0, stream>>>(bufU, x_proj_w, part);
        xpred_k<<<ROWS * KDIM / 4 / 256, 256, 0, stream>>>(part, xdbl);
    }

    // K5: delta = softplus(dts @ dt_proj_w^T + dt_proj_b)   (fp32)
    {
        dim3 g(DIQ / 64, ROWS / 64);
        gemm64<true, 1><<<g, 256, 0, stream>>>(xdbl, dt_proj_w, dt_proj_b, bufD,
                                               ROWS, DIQ, RR, KDIM, RR, DIQ);
    }

    // K6: chunked selective scan -> y (bufA reused)
    {
        int ngrp = DIQ / 4;
        scan1_k<<<BATCH * CCH * ngrp, 64, 0, stream>>>(bufD, bufU, xdbl, A_log, hend, PpH);
        scan_combine_k<<<BATCH * ngrp, 64, 0, stream>>>(hend, PpH);
        scan3_k<<<BATCH * CCH * ngrp, 64, 0, stream>>>(bufD, bufU, xdbl, A_log, Dp, PpH, bufA);
    }

    // K7: layernorm + silu(z) gate -> gate hi/lo
    lngate_k<<<ROWS, 256, 0, stream>>>(bufA, bufZ, ln_w, ln_b, gateH, gateL);

    // K8: out = gate @ Wout   (4096 x 768, K=1536)
    {
        dim3 g(DMQ / 128, ROWS / 128);  // 6 x 32
        gemm_bf3<<<g, 256, 0, stream>>>(gateH, gateL, WoutH, WoutL, out, DIQ, DMQ);
    }
}

// Round 14
// 533.070 us; speedup vs baseline: 2.6145x; 1.0576x over previous
//
#include <hip/hip_runtime.h>
#include <math.h>

#define DMQ 768
#define DIQ 1536
#define LSEQ 2048
#define BATCH 2
#define NST 16
#define RR 48
#define KDIM 80   // R + 2N
#define EPSQ 1e-5f
#define CCH 16    // scan chunks
#define TCH 128   // chunk length (LSEQ / CCH)

typedef __attribute__((ext_vector_type(8))) short short8;
typedef __attribute__((ext_vector_type(4))) float f32x4;

static __device__ __forceinline__ float silu_f(float x) {
    return x / (1.f + __expf(-x));
}
static __device__ __forceinline__ float softplus_f(float x) {
    return (x > 20.f) ? x : log1pf(__expf(x));
}
// bf16 round-to-nearest-even split helpers
static __device__ __forceinline__ ushort f2bf(float v) {
    union { float f; unsigned u; } x; x.f = v;
    unsigned r = x.u + 0x7fffu + ((x.u >> 16) & 1u);
    return (ushort)(r >> 16);
}
static __device__ __forceinline__ float bf2f(ushort h) {
    union { float f; unsigned u; } x; x.u = ((unsigned)h) << 16;
    return x.f;
}

// ---------------------------------------------------------------------------
// K1: residual = x + residual ; xn = rmsnorm(residual)*norm_w -> bf16 hi/lo
// ---------------------------------------------------------------------------
__launch_bounds__(256)
__global__ void rmsnorm_k(const float* __restrict__ x, const float* __restrict__ res,
                          const float* __restrict__ w, float* __restrict__ res_out,
                          ushort* __restrict__ xnH, ushort* __restrict__ xnL) {
    int row = blockIdx.x;
    int tid = threadIdx.x;
    size_t base = (size_t)row * DMQ;
    float v[3];
    float ss = 0.f;
#pragma unroll
    for (int i = 0; i < 3; ++i) {
        int c = tid + i * 256;
        float r = x[base + c] + res[base + c];
        v[i] = r;
        ss = fmaf(r, r, ss);
        res_out[base + c] = r;
    }
#pragma unroll
    for (int off = 1; off < 64; off <<= 1) ss += __shfl_xor(ss, off);
    __shared__ float sbuf[4];
    if ((tid & 63) == 0) sbuf[tid >> 6] = ss;
    __syncthreads();
    float tot = sbuf[0] + sbuf[1] + sbuf[2] + sbuf[3];
    float inv = rsqrtf(tot / (float)DMQ + EPSQ);
#pragma unroll
    for (int i = 0; i < 3; ++i) {
        int c = tid + i * 256;
        float xv = v[i] * inv * w[c];
        ushort hi = f2bf(xv);
        xnH[base + c] = hi;
        xnL[base + c] = f2bf(xv - bf2f(hi));
    }
}

// ---------------------------------------------------------------------------
// Weight transpose + bf16 split: W[K][N] fp32 -> Whi/Wlo [N][K] bf16
// grid (N/32, K/32), 256 threads
// ---------------------------------------------------------------------------
__launch_bounds__(256)
__global__ void wcvt_k(const float* __restrict__ W, ushort* __restrict__ Whi,
                       ushort* __restrict__ Wlo, int K, int N) {
    __shared__ float tile[32][33];
    int n0 = blockIdx.x * 32, k0 = blockIdx.y * 32;
    int t = threadIdx.x;
#pragma unroll
    for (int i = 0; i < 4; ++i) {
        int idx = t + i * 256;
        int r = idx >> 5, c = idx & 31;
        tile[r][c] = W[(size_t)(k0 + r) * N + n0 + c];
    }
    __syncthreads();
#pragma unroll
    for (int i = 0; i < 4; ++i) {
        int idx = t + i * 256;
        int r = idx >> 5, c = idx & 31;   // out row n0+r, col k0+c
        float v = tile[c][r];
        ushort hi = f2bf(v);
        size_t o = (size_t)(n0 + r) * K + k0 + c;
        Whi[o] = hi;
        Wlo[o] = f2bf(v - bf2f(hi));
    }
}

// ---------------------------------------------------------------------------
// Split-bf16 MFMA GEMM: C[M,N] fp32 = (Ah+Al)[M,K] @ (Bh+Bl)[N,K]^T
// PK=72 (>= BK=64; Round-6 bug was PK=40 overflow). 128x128 tile, BK=64,
// 4 waves (2x2), each wave 64x64 = 4x4 frags of 16x16x32.
// ---------------------------------------------------------------------------
__launch_bounds__(256)
__global__ void gemm_bf3(const ushort* __restrict__ Ah, const ushort* __restrict__ Al,
                         const ushort* __restrict__ Bh, const ushort* __restrict__ Bl,
                         float* __restrict__ C, int K, int ldc) {
    constexpr int PK = 72;
    __shared__ ushort lAh[128 * PK], lAl[128 * PK], lBh[128 * PK], lBl[128 * PK];
    const int t = threadIdx.x;
    const int bm = blockIdx.y * 128, bn = blockIdx.x * 128;
    const int lane = t & 63;
    const int wr = ((t >> 6) >> 1) * 64, wc = ((t >> 6) & 1) * 64;
    const int lr = lane & 15, lk = (lane >> 4) * 8;
    const int sr = t >> 3, sc = (t & 7) * 8;
    f32x4 acc[4][4] = {};
    for (int k0 = 0; k0 < K; k0 += 64) {
#pragma unroll
        for (int r = 0; r < 4; ++r) {
            int row = r * 32 + sr;
            size_t ga = (size_t)(bm + row) * K + k0 + sc;
            size_t gb = (size_t)(bn + row) * K + k0 + sc;
            int lo = row * PK + sc;
            *(short8*)&lAh[lo] = *(const short8*)&Ah[ga];
            *(short8*)&lAl[lo] = *(const short8*)&Al[ga];
            *(short8*)&lBh[lo] = *(const short8*)&Bh[gb];
            *(short8*)&lBl[lo] = *(const short8*)&Bl[gb];
        }
        __syncthreads();
#pragma unroll
        for (int kf = 0; kf < 2; ++kf) {
            int ko = kf * 32 + lk;
            short8 ah[4], al[4], bh[4], bl[4];
#pragma unroll
            for (int m = 0; m < 4; ++m) {
                int ro = (wr + m * 16 + lr) * PK + ko;
                ah[m] = *(const short8*)&lAh[ro];
                al[m] = *(const short8*)&lAl[ro];
            }
#pragma unroll
            for (int n = 0; n < 4; ++n) {
                int ro = (wc + n * 16 + lr) * PK + ko;
                bh[n] = *(const short8*)&lBh[ro];
                bl[n] = *(const short8*)&lBl[ro];
            }
#pragma unroll
            for (int m = 0; m < 4; ++m)
#pragma unroll
                for (int n = 0; n < 4; ++n) {
                    acc[m][n] = __builtin_amdgcn_mfma_f32_16x16x32_bf16(ah[m], bh[n], acc[m][n], 0, 0, 0);
                    acc[m][n] = __builtin_amdgcn_mfma_f32_16x16x32_bf16(ah[m], bl[n], acc[m][n], 0, 0, 0);
                    acc[m][n] = __builtin_amdgcn_mfma_f32_16x16x32_bf16(al[m], bh[n], acc[m][n], 0, 0, 0);
                }
        }
        __syncthreads();
    }
    // epilogue: C/D layout col=lane&15, row=(lane>>4)*4+j  [verified m89/m91]
#pragma unroll
    for (int m = 0; m < 4; ++m) {
        int r0 = bm + wr + m * 16 + (lane >> 4) * 4;
#pragma unroll
        for (int n = 0; n < 4; ++n) {
            int cc = bn + wc + n * 16 + lr;
#pragma unroll
            for (int j = 0; j < 4; ++j)
                C[(size_t)(r0 + j) * ldc + cc] = acc[m][n][j];
        }
    }
}

// ---------------------------------------------------------------------------
// Legacy fp32 64x64 GEMM (only dt_proj uses it now: BT=true, EPI=1).
// ---------------------------------------------------------------------------
template <bool BT, int EPI>
__launch_bounds__(256)
__global__ void gemm64(const float* __restrict__ A, const float* __restrict__ B,
                       const float* __restrict__ bias, float* __restrict__ C,
                       int M, int N, int K, int lda, int ldb, int ldc) {
    constexpr int BM = 64, BN = 64, BK = 16;
    __shared__ float As[BK][BM + 4];
    __shared__ float Bs[BK][BN + 4];
    const int tid = threadIdx.x;
    const int tx = tid & 15, ty = tid >> 4;
    const int bm = blockIdx.y * BM;
    const int bn = blockIdx.x * BN;
    float acc[4][4] = {};
    for (int k0 = 0; k0 < K; k0 += BK) {
#pragma unroll
        for (int i = 0; i < 4; ++i) {
            int t = tid + i * 256;
            int m = t >> 4;
            int kk = t & 15;
            As[kk][m] = A[(size_t)(bm + m) * lda + k0 + kk];
        }
#pragma unroll
        for (int i = 0; i < 4; ++i) {
            int t = tid + i * 256;
            if (!BT) {
                int kk = t >> 6;
                int n = t & 63;
                float v = 0.f;
                if (bn + n < N) v = B[(size_t)(k0 + kk) * ldb + bn + n];
                Bs[kk][n] = v;
            } else {
                int n = t >> 4;
                int kk = t & 15;
                float v = 0.f;
                if (bn + n < N) v = B[(size_t)(bn + n) * ldb + k0 + kk];
                Bs[kk][n] = v;
            }
        }
        __syncthreads();
#pragma unroll
        for (int kk = 0; kk < BK; ++kk) {
            float4 av = *(const float4*)&As[kk][ty * 4];
            float4 bv = *(const float4*)&Bs[kk][tx * 4];
            float a[4] = {av.x, av.y, av.z, av.w};
            float b[4] = {bv.x, bv.y, bv.z, bv.w};
#pragma unroll
            for (int i = 0; i < 4; ++i)
#pragma unroll
                for (int j = 0; j < 4; ++j)
                    acc[i][j] = fmaf(a[i], b[j], acc[i][j]);
        }
        __syncthreads();
    }
#pragma unroll
    for (int i = 0; i < 4; ++i) {
        int m = bm + ty * 4 + i;
#pragma unroll
        for (int j = 0; j < 4; ++j) {
            int n = bn + tx * 4 + j;
            if (n < N) {
                float v = acc[i][j];
                if (EPI == 1) v = softplus_f(v + bias[n]);
                C[(size_t)m * ldc + n] = v;
            }
        }
    }
}

// ---------------------------------------------------------------------------
// K4: x_dbl = u @ x_proj_w  (4096 x 80, K=1536), split-K x4.  (validated R13)
// ---------------------------------------------------------------------------
__launch_bounds__(256)
__global__ void xp_k(const float* __restrict__ u, const float* __restrict__ xW,
                     float* __restrict__ part) {
    __shared__ float wt[80 * 68];
    const int t = threadIdx.x;
    const int r = blockIdx.x * 16 + (t >> 4);
    const int c0 = (t & 15) * 5;
    const int k0s = blockIdx.y * 384;
    float acc[5] = {0.f, 0.f, 0.f, 0.f, 0.f};
    for (int ch = 0; ch < 6; ++ch) {
        int kc = k0s + ch * 64;
        __syncthreads();
#pragma unroll
        for (int i = 0; i < 20; ++i) {
            int idx = t + i * 256;       // 5120 = 64k x 80c
            int c = idx % 80;
            int k = idx / 80;
            wt[c * 68 + k] = xW[(size_t)(kc + k) * KDIM + c];
        }
        __syncthreads();
        const float4* pa = (const float4*)&u[(size_t)r * DIQ + kc];
#pragma unroll
        for (int i = 0; i < 16; ++i) {
            float4 av = pa[i];
#pragma unroll
            for (int j = 0; j < 5; ++j) {
                float4 wv = *(const float4*)&wt[(c0 + j) * 68 + i * 4];
                acc[j] = fmaf(av.x, wv.x, acc[j]);
                acc[j] = fmaf(av.y, wv.y, acc[j]);
                acc[j] = fmaf(av.z, wv.z, acc[j]);
                acc[j] = fmaf(av.w, wv.w, acc[j]);
            }
        }
    }
    float* po = &part[((size_t)blockIdx.y * 4096 + r) * KDIM + c0];
#pragma unroll
    for (int j = 0; j < 5; ++j) po[j] = acc[j];
}

__launch_bounds__(256)
__global__ void xpred_k(const float* __restrict__ part, float* __restrict__ xdbl) {
    int i = blockIdx.x * 256 + threadIdx.x;      // 81920 float4s
    const int S4 = 4096 * KDIM / 4;              // 81920
    const float4* p = (const float4*)part;
    float4 a = p[i], b = p[i + S4], c = p[i + 2 * S4], d = p[i + 3 * S4];
    float4 o;
    o.x = a.x + b.x + c.x + d.x;
    o.y = a.y + b.y + c.y + d.y;
    o.z = a.z + b.z + c.z + d.z;
    o.w = a.w + b.w + c.w + d.w;
    ((float4*)xdbl)[i] = o;
}

// ---------------------------------------------------------------------------
// K3: depthwise causal-padded conv (kernel 3, pad 1) + bias + silu
// ---------------------------------------------------------------------------
__launch_bounds__(256)
__global__ void conv_silu_k(const float* __restrict__ xc, const float* __restrict__ cw,
                            const float* __restrict__ cb, float* __restrict__ u) {
    int idx = blockIdx.x * 256 + threadIdx.x;
    const int nd4 = DIQ / 4;
    int row = idx / nd4;
    int d = (idx - row * nd4) * 4;
    int l = row & (LSEQ - 1);
    const float* p = xc + (size_t)row * DIQ + d;
    float a0[4] = {0.f, 0.f, 0.f, 0.f};
    float a1[4];
    float a2[4] = {0.f, 0.f, 0.f, 0.f};
    *(float4*)a1 = *(const float4*)p;
    if (l > 0) *(float4*)a0 = *(const float4*)(p - DIQ);
    if (l < LSEQ - 1) *(float4*)a2 = *(const float4*)(p + DIQ);
    float4 ov;
    float* o = (float*)&ov;
#pragma unroll
    for (int j = 0; j < 4; ++j) {
        float s = cb[d + j];
        s = fmaf(a0[j], cw[(d + j) * 3 + 0], s);
        s = fmaf(a1[j], cw[(d + j) * 3 + 1], s);
        s = fmaf(a2[j], cw[(d + j) * 3 + 2], s);
        o[j] = silu_f(s);
    }
    *(float4*)(u + (size_t)row * DIQ + d) = ov;
}

// ---------------------------------------------------------------------------
// Chunked selective scan.
// R14 change: 256-thread blocks covering 16 channels (4 waves x 4 channels).
// R13 PMC diagnosis: 64-thread blocks touched 16B of each 64B line of
// delta/u (FETCH 201MB vs ~54MB useful, 3.7x over-fetch, HBM-bound at 23%
// peak). Merging 4 channel-groups into one block puts the whole 64B line's
// consumers on one CU -> L1 serves 3 of 4 waves; y stores combine to 64B.
// Per-lane layout unchanged: d = dg*16 + wave*4 + (lane>>4), n = lane&15.
// ---------------------------------------------------------------------------
__launch_bounds__(256)
__global__ void scan1_k(const float* __restrict__ delta, const float* __restrict__ u,
                        const float* __restrict__ xdbl, const float* __restrict__ Alog,
                        float* __restrict__ hend, float* __restrict__ Pp) {
    const int ngrp = DIQ / 16;  // 96
    int blk = blockIdx.x;
    int dg = blk % ngrp;
    int c = (blk / ngrp) % CCH;
    int b = blk / (ngrp * CCH);
    int tid = threadIdx.x;
    int lane = tid & 63;
    int d = dg * 16 + (tid >> 6) * 4 + (lane >> 4);
    int n = lane & 15;
    float a = -__expf(Alog[d * NST + n]);
    size_t r0 = (size_t)b * LSEQ + (size_t)c * TCH;
    const float* pd = delta + r0 * DIQ + d;
    const float* pu = u + r0 * DIQ + d;
    const float* pb = xdbl + r0 * KDIM + RR + n;
    float h = 0.f, P = 1.f;
    float dlt = *pd, uu = *pu, bv = *pb;
    for (int t = 0; t < TCH; ++t) {
        float dlt_n = 0.f, uu_n = 0.f, bv_n = 0.f;
        if (t + 1 < TCH) {
            pd += DIQ; pu += DIQ; pb += KDIM;
            dlt_n = *pd; uu_n = *pu; bv_n = *pb;
        }
        float dA = __expf(dlt * a);
        h = fmaf(dA, h, dlt * uu * bv);
        P *= dA;
        dlt = dlt_n; uu = uu_n; bv = bv_n;
    }
    size_t idx = (((size_t)b * CCH + c) * DIQ + d) * NST + n;
    hend[idx] = h;
    Pp[idx] = P;
}

__launch_bounds__(64)
__global__ void scan_combine_k(const float* __restrict__ hend, float* __restrict__ PpH) {
    const int ngrp = DIQ / 4;
    int blk = blockIdx.x;
    int b = blk / ngrp;
    int dg = blk % ngrp;
    int d = dg * 4 + (threadIdx.x >> 4);
    int n = threadIdx.x & 15;
    size_t base = ((size_t)b * CCH) * DIQ * NST + (size_t)d * NST + n;
    const size_t cs = (size_t)DIQ * NST;
    float H = 0.f;
#pragma unroll
    for (int c = 0; c < CCH; ++c) {
        size_t o = base + c * cs;
        float P = PpH[o];
        PpH[o] = H;                 // Hstart (in-place over Pp)
        H = fmaf(P, H, hend[o]);
    }
}

__launch_bounds__(256)
__global__ void scan3_k(const float* __restrict__ delta, const float* __restrict__ u,
                        const float* __restrict__ xdbl, const float* __restrict__ Alog,
                        const float* __restrict__ Dp, const float* __restrict__ Hstart,
                        float* __restrict__ y) {
    const int ngrp = DIQ / 16;  // 96
    int blk = blockIdx.x;
    int dg = blk % ngrp;
    int c = (blk / ngrp) % CCH;
    int b = blk / (ngrp * CCH);
    int tid = threadIdx.x;
    int lane = tid & 63;
    int d = dg * 16 + (tid >> 6) * 4 + (lane >> 4);
    int n = lane & 15;
    float a = -__expf(Alog[d * NST + n]);
    float Dd = Dp[d];
    size_t idx = (((size_t)b * CCH + c) * DIQ + d) * NST + n;
    float h = Hstart[idx];
    size_t r0 = (size_t)b * LSEQ + (size_t)c * TCH;
    const float* pd = delta + r0 * DIQ + d;
    const float* pu = u + r0 * DIQ + d;
    const float* pb = xdbl + r0 * KDIM + RR + n;
    const float* pc = xdbl + r0 * KDIM + RR + NST + n;
    float* py = y + r0 * DIQ + d;
    float dlt = *pd, uu = *pu, bv = *pb, cv = *pc;
    for (int t = 0; t < TCH; ++t) {
        float dlt_n = 0.f, uu_n = 0.f, bv_n = 0.f, cv_n = 0.f;
        if (t + 1 < TCH) {
            pd += DIQ; pu += DIQ; pb += KDIM; pc += KDIM;
            dlt_n = *pd; uu_n = *pu; bv_n = *pb; cv_n = *pc;
        }
        float dA = __expf(dlt * a);
        h = fmaf(dA, h, dlt * uu * bv);
        float yc = h * cv;
        yc += __shfl_xor(yc, 1);
        yc += __shfl_xor(yc, 2);
        yc += __shfl_xor(yc, 4);
        yc += __shfl_xor(yc, 8);
        if (n == 0) py[(size_t)t * DIQ] = fmaf(uu, Dd, yc);
        dlt = dlt_n; uu = uu_n; bv = bv_n; cv = cv_n;
    }
}

// ---------------------------------------------------------------------------
// K7: layernorm(y)*ln_w+ln_b, gated by silu(z) -> bf16 hi/lo
// ---------------------------------------------------------------------------
__launch_bounds__(256)
__global__ void lngate_k(const float* __restrict__ y, const float* __restrict__ z,
                         const float* __restrict__ lw, const float* __restrict__ lb,
                         ushort* __restrict__ gH, ushort* __restrict__ gL) {
    int row = blockIdx.x;
    int tid = threadIdx.x;
    size_t ybase = (size_t)row * DIQ;
    float v[6];
    float s = 0.f, sq = 0.f;
#pragma unroll
    for (int i = 0; i < 6; ++i) {
        int c = tid + i * 256;
        float t = y[ybase + c];
        v[i] = t;
        s += t;
        sq = fmaf(t, t, sq);
    }
#pragma unroll
    for (int off = 1; off < 64; off <<= 1) {
        s += __shfl_xor(s, off);
        sq += __shfl_xor(sq, off);
    }
    __shared__ float ssb[4], sqb[4];
    if ((tid & 63) == 0) {
        ssb[tid >> 6] = s;
        sqb[tid >> 6] = sq;
    }
    __syncthreads();
    s = ssb[0] + ssb[1] + ssb[2] + ssb[3];
    sq = sqb[0] + sqb[1] + sqb[2] + sqb[3];
    float mu = s / (float)DIQ;
    float var = sq / (float)DIQ - mu * mu;
    float inv = rsqrtf(var + EPSQ);
#pragma unroll
    for (int i = 0; i < 6; ++i) {
        int c = tid + i * 256;
        float t = (v[i] - mu) * inv * lw[c] + lb[c];
        float g = t * silu_f(z[ybase + c]);
        ushort hi = f2bf(g);
        gH[ybase + c] = hi;
        gL[ybase + c] = f2bf(g - bf2f(hi));
    }
}

// ---------------------------------------------------------------------------
extern "C" void kernel_launch(void* const* d_in, const int* in_sizes, int n_in,
                              void* d_out, int out_size, void* d_ws, size_t ws_size,
                              hipStream_t stream) {
    const float* x         = (const float*)d_in[0];
    const float* residual  = (const float*)d_in[1];
    const float* norm_w    = (const float*)d_in[2];
    const float* in_proj_w = (const float*)d_in[3];
    const float* conv_w    = (const float*)d_in[4];
    const float* conv_b    = (const float*)d_in[5];
    const float* x_proj_w  = (const float*)d_in[6];
    const float* dt_proj_w = (const float*)d_in[7];
    const float* dt_proj_b = (const float*)d_in[8];
    const float* A_log     = (const float*)d_in[9];
    const float* Dp        = (const float*)d_in[10];
    const float* ln_w      = (const float*)d_in[11];
    const float* ln_b      = (const float*)d_in[12];
    const float* out_proj_w= (const float*)d_in[13];

    float* out = (float*)d_out;                               // (B,L,DM)
    float* res_out = out + (size_t)BATCH * LSEQ * DMQ;        // (B,L,DM)

    const int ROWS = BATCH * LSEQ;                 // 4096
    const size_t RF = (size_t)ROWS * DIQ;          // 6291456
    const size_t SCN = (size_t)BATCH * CCH * DIQ * NST;  // 786432

    float* bufA = (float*)d_ws;          // xc (K2-K3), then y (K6-K7)
    float* bufZ = bufA + RF;             // z (K2-K7)
    float* bufU = bufZ + RF;             // u
    float* bufD = bufU + RF;             // delta
    float* xdbl = bufD + RF;             // ROWS*KDIM
    float* hend = xdbl + (size_t)ROWS * KDIM;
    float* PpH  = hend + SCN;            // Pp, then Hstart in-place
    float* part = hend;                  // xp partials overlap hend+PpH
    ushort* WoutH = (ushort*)(PpH + SCN);
    ushort* WoutL = WoutH + (size_t)DMQ * DIQ;     // 768*1536
    ushort* Rbase = WoutL + (size_t)DMQ * DIQ;
    // early use of R: xn hi/lo + Win hi/lo ; late use: gate hi/lo
    ushort* xnH  = Rbase;
    ushort* xnL  = xnH + (size_t)ROWS * DMQ;
    ushort* WinH = xnL + (size_t)ROWS * DMQ;
    ushort* WinL = WinH + (size_t)DMQ * 2 * DIQ;   // 768*3072
    ushort* gateH = Rbase;
    ushort* gateL = gateH + (size_t)ROWS * DIQ;

    // weight conversion (every launch; ws is re-poisoned each call)
    wcvt_k<<<dim3(2 * DIQ / 32, DMQ / 32), 256, 0, stream>>>(in_proj_w, WinH, WinL, DMQ, 2 * DIQ);
    wcvt_k<<<dim3(DMQ / 32, DIQ / 32), 256, 0, stream>>>(out_proj_w, WoutH, WoutL, DIQ, DMQ);

    // K1: add + RMSNorm -> xn hi/lo
    rmsnorm_k<<<ROWS, 256, 0, stream>>>(x, residual, norm_w, res_out, xnH, xnL);

    // K2: xc = xn @ Win[:, :DI] ; z = xn @ Win[:, DI:]
    {
        dim3 g(DIQ / 128, ROWS / 128);  // 12 x 32
        gemm_bf3<<<g, 256, 0, stream>>>(xnH, xnL, WinH, WinL, bufA, DMQ, DIQ);
        size_t off = (size_t)DIQ * DMQ;
        gemm_bf3<<<g, 256, 0, stream>>>(xnH, xnL, WinH + off, WinL + off, bufZ, DMQ, DIQ);
    }

    // K3: depthwise conv + bias + silu -> u
    conv_silu_k<<<ROWS * (DIQ / 4) / 256, 256, 0, stream>>>(bufA, conv_w, conv_b, bufU);

    // K4: x_dbl = u @ x_proj_w  (split-K x4 + reduce)
    {
        dim3 g(ROWS / 16, 4);           // 256 x 4 = 1024 blocks
        xp_k<<<g, 256, 0, stream>>>(bufU, x_proj_w, part);
        xpred_k<<<ROWS * KDIM / 4 / 256, 256, 0, stream>>>(part, xdbl);
    }

    // K5: delta = softplus(dts @ dt_proj_w^T + dt_proj_b)   (fp32)
    {
        dim3 g(DIQ / 64, ROWS / 64);
        gemm64<true, 1><<<g, 256, 0, stream>>>(xdbl, dt_proj_w, dt_proj_b, bufD,
                                               ROWS, DIQ, RR, KDIM, RR, DIQ);
    }

    // K6: chunked selective scan -> y (bufA reused)
    {
        int ngrp16 = DIQ / 16;  // 96
        scan1_k<<<BATCH * CCH * ngrp16, 256, 0, stream>>>(bufD, bufU, xdbl, A_log, hend, PpH);
        scan_combine_k<<<BATCH * (DIQ / 4), 64, 0, stream>>>(hend, PpH);
        scan3_k<<<BATCH * CCH * ngrp16, 256, 0, stream>>>(bufD, bufU, xdbl, A_log, Dp, PpH, bufA);
    }

    // K7: layernorm + silu(z) gate -> gate hi/lo
    lngate_k<<<ROWS, 256, 0, stream>>>(bufA, bufZ, ln_w, ln_b, gateH, gateL);

    // K8: out = gate @ Wout   (4096 x 768, K=1536)
    {
        dim3 g(DMQ / 128, ROWS / 128);  // 6 x 32
        gemm_bf3<<<g, 256, 0, stream>>>(gateH, gateL, WoutH, WoutL, out, DIQ, DMQ);
    }
}